// Round 11
// baseline (848.746 us; speedup 1.0000x reference)
//
#include <hip/hip_runtime.h>
#include <math.h>

typedef unsigned short u16;
typedef short bf16x4 __attribute__((ext_vector_type(4)));
typedef short bf16x8 __attribute__((ext_vector_type(8)));
typedef float f32x16 __attribute__((ext_vector_type(16)));

#define NN 20000
#define PP 3
#define TLP 10
#define TNS 20
#define DD 128
#define EE 640000

__device__ __forceinline__ float bf2f(u16 u) {
  union { unsigned u; float f; } v; v.u = ((unsigned)u) << 16; return v.f;
}
__device__ __forceinline__ u16 f2bf(float f) {
  union { float f; unsigned u; } v; v.f = f;
  unsigned r = v.u + 0x7fffu + ((v.u >> 16) & 1u);
  return (u16)(r >> 16);
}
// HW bf16 convert via compiler-visible fptrunc (RNE, hazard-managed).
// Safe on MFMA accumulator reads (unlike inline-asm cvtpk).
__device__ __forceinline__ short f2bf_hw(float f) {
  __bf16 b = (__bf16)f;
  return (short)__builtin_bit_cast(unsigned short, b);
}
__device__ __forceinline__ float loadf(const void* p, size_t i, int isf) {
  return isf ? ((const float*)p)[i] : bf2f(((const u16*)p)[i]);
}
// exp2-domain transcendentals via intrinsics (hazards compiler-managed)
__device__ __forceinline__ float fex2(float x) { return __builtin_amdgcn_exp2f(x); }
__device__ __forceinline__ float frcp(float x) { return __builtin_amdgcn_rcpf(x); }
// packed bf16 convert — ONLY on plain-VALU-produced values (m214-proven).
// NEVER on direct MFMA accumulator reads (R1/R2 corruption: asm consumer of
// MFMA dst misses mandatory wait-states).
__device__ __forceinline__ unsigned cvtpk(float lo, float hi) {
  unsigned r; asm("v_cvt_pk_bf16_f32 %0, %1, %2" : "=v"(r) : "v"(lo), "v"(hi));
  return r;
}

// ------------------------------------------------------------- dtype detect
// + zero the sort bins (saves a launch)
__global__ void k_detect(const void* probe, int* flag, int* bins) {
  __shared__ int any;
  if (threadIdx.x == 0) any = 0;
  __syncthreads();
  if (threadIdx.x < 128) bins[threadIdx.x] = 0;
  const u16* p = (const u16*)probe;
  int bad = 0;
  for (int i = threadIdx.x; i < 4096; i += 256) {
    int e = (p[2 * i] >> 7) & 0xFF;
    if (e >= 0x9F) bad = 1;
  }
  if (bad) atomicOr(&any, 1);
  __syncthreads();
  if (threadIdx.x == 0) flag[0] = any;  // 1 = f32, 0 = bf16
}

// ------------------------------------------------------------- converters
struct CvtJobs {
  const void* src[16];
  int off[16];
  int n[16];
};

struct CvtJobsB {
  const void* src[12];
  int off[12];
  int n[12];
  int thr[12];     // i < thr -> scA else scB
  float scA[12];
  float scB[12];
};

// merged: [0,768) bf16 jobs; [768,784) float jobs; [784,..) counts init.
// jobs 0,1 (embeddings, scale=1) are identity copies when input is already
// bf16 -> skip; gru selects the raw input pointer by flag.
__global__ void k_cvtb(CvtJobsB j, CvtJobs jf, u16* __restrict__ dst,
                       float* __restrict__ fdst, int* __restrict__ counts,
                       const int* flag) {
  const int isf = flag[0];
  if (blockIdx.x >= 12 * 64 + 16) {
    int i = (blockIdx.x - (12 * 64 + 16)) * 256 + threadIdx.x;
    if (i < NN) counts[i] = 0;
    return;
  }
  if (blockIdx.x >= 12 * 64) {
    const int job = blockIdx.x - 12 * 64;
    const void* s = jf.src[job];
    float* d = fdst + jf.off[job];
    const int n = jf.n[job];
    for (int i = threadIdx.x; i < n; i += 256) d[i] = loadf(s, i, isf);
    return;
  }
  const int job = blockIdx.x >> 6;
  if (job < 2 && !isf) return;  // bf16 input: embeddings used in place
  const int chunk = blockIdx.x & 63;
  const void* s = j.src[job];
  u16* d = dst + j.off[job];
  const int n = j.n[job];
  const int thr = j.thr[job];
  const float sA = j.scA[job], sB = j.scB[job];
  for (int i = chunk * 256 + threadIdx.x; i < n; i += 64 * 256)
    d[i] = f2bf(loadf(s, i, isf) * (i < thr ? sA : sB));
}

// ------------------------------------------------------------- length sort
// ballot-aggregated counting sort: one atomic per wave per bin.
// merged LP+NS histogram; tail blocks run the counts-only EDGE histogram
// (lenboth is only 235 blocks — machine is idle; atomic-bound hist overlaps
// the VALU-bound ballot loops instead of extending gru's tail).
__global__ void k_lenboth(const int* __restrict__ lensLP,
                          const int* __restrict__ lensNS,
                          int* __restrict__ bins,
                          const int* __restrict__ e_dst,
                          int* __restrict__ counts) {
  const int nLen = (PP * NN + 255) / 256;
  if ((int)blockIdx.x >= nLen) {
    int e = ((int)blockIdx.x - nLen) * 256 + threadIdx.x;
    if (e < EE) atomicAdd(&counts[e_dst[e]], 1);
    return;
  }
  int sg = blockIdx.x * 256 + threadIdx.x;
  int lane = threadIdx.x & 63;
  int binL = 0, binN = 0;
  if (sg < PP * NN) binL = lensLP[(sg % NN) * PP + sg / NN];
  if (sg < NN) binN = lensNS[sg];
  for (int b = 1; b <= TLP; ++b) {
    unsigned long long m = __ballot(binL == b);
    if (m) {
      int leader = (int)(__ffsll((long long)m) - 1);
      if (lane == leader) atomicAdd(&bins[b], (int)__popcll(m));
    }
  }
  for (int b = 1; b <= TNS; ++b) {
    unsigned long long m = __ballot(binN == b);
    if (m) {
      int leader = (int)(__ffsll((long long)m) - 1);
      if (lane == leader) atomicAdd(&bins[64 + b], (int)__popcll(m));
    }
  }
}

// block 0: both bin scans. block 1: mp-head combined weights
//   Wc[o][k] = sum_d mp2_W[o][d]*mp1_W[d][k]; bc[o] = mp2_W[o]·b_mp1 + b_mp2[o]
//   (valid: no activation between mp1 and mp2 in the reference)
__global__ void k_binscan2(int* __restrict__ bins,
                           const float* __restrict__ w_mp2,
                           const float* __restrict__ b_mp1_,
                           const float* __restrict__ b_mp2_,
                           const void* __restrict__ mp1raw,
                           float* __restrict__ Wc, const int* flag) {
  if (blockIdx.x == 0) {
    if (threadIdx.x == 0) {
      int acc = 0;
      for (int k = 0; k < 32; ++k) { bins[32 + k] = acc; acc += bins[k]; }
    }
    if (threadIdx.x == 1) {
      int acc = 0;
      for (int k = 0; k < 32; ++k) { bins[96 + k] = acc; acc += bins[64 + k]; }
    }
    return;
  }
  const int isf = flag[0];
  const int t = threadIdx.x;          // 0..255
  const int o = t >> 7, k = t & 127;
  float acc = 0.f;
  for (int d2 = 0; d2 < 128; ++d2)
    acc += w_mp2[o * 128 + d2] * loadf(mp1raw, (size_t)d2 * 128 + k, isf);
  Wc[t] = acc;
  if (t < 2) {
    float bacc = b_mp2_[t];
    for (int d2 = 0; d2 < 128; ++d2) bacc += w_mp2[t * 128 + d2] * b_mp1_[d2];
    Wc[256 + t] = bacc;
  }
}

__global__ void k_lenfillboth(const int* __restrict__ lensLP,
                              const int* __restrict__ lensNS,
                              int* __restrict__ bins,
                              int* __restrict__ permLP,
                              int* __restrict__ permNS) {
  int sg = blockIdx.x * 256 + threadIdx.x;
  int lane = threadIdx.x & 63;
  int binL = 0, binN = 0;
  if (sg < PP * NN) binL = lensLP[(sg % NN) * PP + sg / NN];
  if (sg < NN) binN = lensNS[sg];
  for (int b = 1; b <= TLP; ++b) {
    unsigned long long m = __ballot(binL == b);
    if (m) {
      int leader = (int)(__ffsll((long long)m) - 1);
      int base = 0;
      if (lane == leader) base = atomicAdd(&bins[32 + b], (int)__popcll(m));
      base = __shfl(base, leader);
      if (binL == b) {
        int rank = (int)__popcll(m & ((1ull << lane) - 1ull));
        permLP[base + rank] = sg;
      }
    }
  }
  for (int b = 1; b <= TNS; ++b) {
    unsigned long long m = __ballot(binN == b);
    if (m) {
      int leader = (int)(__ffsll((long long)m) - 1);
      int base = 0;
      if (lane == leader) base = atomicAdd(&bins[96 + b], (int)__popcll(m));
      base = __shfl(base, leader);
      if (binN == b) {
        int rank = (int)__popcll(m & ((1ull << lane) - 1ull));
        permNS[base + rank] = sg;
      }
    }
  }
}

// ---------------------------------------------------------------- GRU v13
// gru body unchanged (control). Block 0 runs the CSR offset scan (hist
// completed in lenboth, previous launch; scan output first read in lp_fc's
// fill tail, next launch) — hides the former k_scan launch entirely.
__global__ __launch_bounds__(512, 2) void k_gru5(
    const int* __restrict__ permLP, const int* __restrict__ permNS, int nbNS,
    const u16* __restrict__ embLPc, const u16* __restrict__ embNSc,
    const u16* __restrict__ embLPr, const u16* __restrict__ embNSr,
    const int* __restrict__ idxLP, const int* __restrict__ idxNS,
    const int* __restrict__ lenLP, const int* __restrict__ lenNS,
    const u16* __restrict__ WihLP, const u16* __restrict__ WhhLP,
    const u16* __restrict__ WihNS, const u16* __restrict__ WhhNS,
    const float* __restrict__ bihLP, const float* __restrict__ bhhLP,
    const float* __restrict__ bihNS, const float* __restrict__ bhhNS,
    u16* __restrict__ HoutLP, u16* __restrict__ HoutNS, int nbLP,
    const int* __restrict__ counts, int* __restrict__ startA,
    int* __restrict__ cursorE, const int* __restrict__ flag) {
  __shared__ u16 xp[2][3][128][36];   // [slot][gate][d][m] bf16, b64-packed
  __shared__ u16 Hbf2[2][32][132];    // [slot][m][d], pad 132
  __shared__ int ivs[TNS][32];
  __shared__ int rowv[32], outv[32], lenv_s[32];
  __shared__ int Tbs;

  const int tid = threadIdx.x;
  if (blockIdx.x == 0) {
    // CSR offset scan (single block; all 512 threads hit both barriers)
    int* part = (int*)ivs;  // 256-int scratch
    const int C = (NN + 255) / 256;
    if (tid < 256) {
      int base = tid * C;
      int s = 0;
      for (int k = 0; k < C; ++k) {
        int i2 = base + k;
        s += (i2 < NN) ? counts[i2] : 0;
      }
      part[tid] = s;
    }
    __syncthreads();
    if (tid == 0) {
      int acc = 0;
      for (int k = 0; k < 256; ++k) { int v = part[k]; part[k] = acc; acc += v; }
    }
    __syncthreads();
    if (tid < 256) {
      int run = part[tid];
      int base = tid * C;
      for (int k = 0; k < C; ++k) {
        int i2 = base + k;
        if (i2 < NN) {
          int c = counts[i2];
          startA[i2] = run;
          cursorE[i2] = run;
          run += c;
        }
      }
      if (tid == 255) startA[NN] = run;
    }
    return;
  }
  const int bid = blockIdx.x - 1;
  const int isf = flag[0];
  const int isNS = bid < nbNS;
  // longest-first: NS family first, descending within each family
  const int chunk = isNS ? (nbNS - 1 - bid) : (nbLP - 1 - (bid - nbNS));
  const int* perm = isNS ? (permNS + chunk * 32) : (permLP + chunk * 32);
  // bf16 input: embeddings used directly from d_in (identity copy skipped)
  const u16* embbf = isNS ? (isf ? embNSc : embNSr) : (isf ? embLPc : embLPr);
  const int* idx = isNS ? idxNS : idxLP;
  const int* lens = isNS ? lenNS : lenLP;
  const u16* Wih = isNS ? WihNS : WihLP;
  const u16* Whh = isNS ? WhhNS : WhhLP;
  const float* bih = isNS ? bihNS : bihLP;
  const float* bhh = isNS ? bhhNS : bhhLP;
  u16* Hout = isNS ? HoutNS : HoutLP;
  const int T = isNS ? TNS : TLP;

  const int w = tid >> 6, lane = tid & 63;
  const int l31 = lane & 31, lh = lane >> 5;
  const int role = w >> 2;  // 0 = X producer, 1 = H consumer
  const int j = w & 3;
  const int d = 32 * j + l31;

  if (tid < 32) {
    int sg = perm[tid];
    int row = isNS ? sg : ((sg % NN) * PP + sg / NN);
    rowv[tid] = row;
    outv[tid] = sg;
    lenv_s[tid] = lens[row];
  }
  __syncthreads();
  if (tid == 0) {
    int m = 1;
    for (int k = 0; k < 32; ++k) m = max(m, lenv_s[k]);
    Tbs = m;
  }
  __syncthreads();
  const int Tb = Tbs;

  for (int z = tid; z < Tb * 32; z += 512) {
    int s = z & 31, t = z >> 5;
    ivs[t][s] = idx[(size_t)rowv[s] * T + t];
  }
  // zero Hbf2 slot 0 (32*132 u16 = 4224 elems = 2112 u32)
  for (int z = tid; z < 2112; z += 512) ((unsigned*)Hbf2[0])[z] = 0u;

  bf16x8 wf[24];
  {
    const u16* Ws = role ? Whh : Wih;
#pragma unroll
    for (int g = 0; g < 3; ++g)
#pragma unroll
      for (int kb = 0; kb < 8; ++kb)
        wf[g * 8 + kb] =
            *(const bf16x8*)(Ws + (size_t)(128 * g + d) * 128 + kb * 16 + lh * 8);
  }
  // exp2-domain bias folding into accumulator inits:
  //  X waves: a0 += SA*(bir+bhr), a1 += SA*(biz+bhz), a2 += SN*bin
  //  H waves: a2 += SN*bhn  (stays inside the r* multiply)
  const float SA = -1.44269504088896f;   // -log2(e)
  const float SN = -2.88539008177793f;   // -2*log2(e)
  float ib0, ib1, ib2;
  if (!role) {
    ib0 = SA * (bih[d] + bhh[d]);
    ib1 = SA * (bih[128 + d] + bhh[128 + d]);
    ib2 = SN * bih[256 + d];
  } else {
    ib0 = 0.f;
    ib1 = 0.f;
    ib2 = SN * bhh[256 + d];
  }

  __syncthreads();
  int lenr[16];
#pragma unroll
  for (int rg = 0; rg < 16; ++rg)
    lenr[rg] = lenv_s[(rg & 3) + 8 * (rg >> 2) + 4 * lh];

  float h[16];
#pragma unroll
  for (int rg = 0; rg < 16; ++rg) h[rg] = 0.f;

  for (int i = 0; i <= Tb; ++i) {
    if (!role) {
      if (i < Tb) {
        bf16x8 Xf[8];
        const u16* erow = embbf + (size_t)ivs[i][l31] * 128 + lh * 8;
#pragma unroll
        for (int kb = 0; kb < 8; ++kb) Xf[kb] = *(const bf16x8*)(erow + kb * 16);
        f32x16 a0 = (f32x16)(ib0), a1 = (f32x16)(ib1), a2 = (f32x16)(ib2);
#pragma unroll
        for (int kb = 0; kb < 8; ++kb) {
          a0 = __builtin_amdgcn_mfma_f32_32x32x16_bf16(Xf[kb], wf[kb], a0, 0, 0, 0);
          a1 = __builtin_amdgcn_mfma_f32_32x32x16_bf16(Xf[kb], wf[8 + kb], a1, 0, 0, 0);
          a2 = __builtin_amdgcn_mfma_f32_32x32x16_bf16(Xf[kb], wf[16 + kb], a2, 0, 0, 0);
        }
        const int sl = i & 1;
        // packed b64 writes: quad rq -> m base 8rq+4lh (4 consecutive m)
        // MFMA acc reads via compiler-visible HW bf16 cast (hazard-safe)
#pragma unroll
        for (int rq = 0; rq < 4; ++rq) {
          int mo = 8 * rq + 4 * lh;
          bf16x4 p0, p1, p2;
#pragma unroll
          for (int q = 0; q < 4; ++q) {
            p0[q] = f2bf_hw(a0[4 * rq + q]);
            p1[q] = f2bf_hw(a1[4 * rq + q]);
            p2[q] = f2bf_hw(a2[4 * rq + q]);
          }
          *(bf16x4*)(&xp[sl][0][d][mo]) = p0;
          *(bf16x4*)(&xp[sl][1][d][mo]) = p1;
          *(bf16x4*)(&xp[sl][2][d][mo]) = p2;
        }
      }
    } else {
      if (i >= 1) {
        const int rs = (i - 1) & 1, wsl = i & 1;
        bf16x8 Hf[8];
#pragma unroll
        for (int kb = 0; kb < 8; ++kb) {
          bf16x4 lo = *(const bf16x4*)(&Hbf2[rs][l31][16 * kb + 8 * lh]);
          bf16x4 hi = *(const bf16x4*)(&Hbf2[rs][l31][16 * kb + 8 * lh + 4]);
          Hf[kb] = __builtin_shufflevector(lo, hi, 0, 1, 2, 3, 4, 5, 6, 7);
        }
        f32x16 a0 = (f32x16)(ib0), a1 = (f32x16)(ib1), a2 = (f32x16)(ib2);
#pragma unroll
        for (int kb = 0; kb < 8; ++kb) {
          a0 = __builtin_amdgcn_mfma_f32_32x32x16_bf16(Hf[kb], wf[kb], a0, 0, 0, 0);
          a1 = __builtin_amdgcn_mfma_f32_32x32x16_bf16(Hf[kb], wf[8 + kb], a1, 0, 0, 0);
          a2 = __builtin_amdgcn_mfma_f32_32x32x16_bf16(Hf[kb], wf[16 + kb], a2, 0, 0, 0);
        }
        const int t = i - 1;
#pragma unroll
        for (int rq = 0; rq < 4; ++rq) {
          int mo = 8 * rq + 4 * lh;
          bf16x4 x0 = *(const bf16x4*)(&xp[rs][0][d][mo]);
          bf16x4 x1 = *(const bf16x4*)(&xp[rs][1][d][mo]);
          bf16x4 x2 = *(const bf16x4*)(&xp[rs][2][d][mo]);
          float hq[4];
#pragma unroll
          for (int q = 0; q < 4; ++q) {
            int rg = 4 * rq + q;
            // operands in -log2e scaled domain:
            //   sigma(pre) = rcp(1 + 2^(SA*pre)), tanh(y) = 2*rcp(1+2^(SN*y)) - 1
            float r = frcp(1.f + fex2(a0[rg] + bf2f((u16)x0[q])));
            float z = frcp(1.f + fex2(a1[rg] + bf2f((u16)x1[q])));
            float s = fmaf(r, a2[rg], bf2f((u16)x2[q]));
            float nn_ = fmaf(2.f, frcp(1.f + fex2(s)), -1.f);
            float hnew = fmaf(z, h[rg] - nn_, nn_);
            h[rg] = (t < lenr[rg]) ? hnew : h[rg];  // pack_padded mask
            hq[q] = h[rg];
          }
          // cvtpk on plain VALU values (cndmask outputs) — proven-safe
          unsigned pa = cvtpk(hq[0], hq[1]);
          unsigned pb = cvtpk(hq[2], hq[3]);
          Hbf2[wsl][mo + 0][d] = (u16)pa;
          Hbf2[wsl][mo + 1][d] = (u16)(pa >> 16);
          Hbf2[wsl][mo + 2][d] = (u16)pb;
          Hbf2[wsl][mo + 3][d] = (u16)(pb >> 16);
        }
      }
    }
    __syncthreads();
  }

  if (role) {
#pragma unroll
    for (int rg = 0; rg < 16; ++rg) {
      int m = (rg & 3) + 8 * (rg >> 2) + 4 * lh;
      Hout[(size_t)outv[m] * 128 + d] = f2bf(h[rg]);
    }
  }
}

// ---------------------------------------------------------------- GEMM (MFMA, LDS-free)
// 128-thr blocks, 32-row tiles. blocks >= gemmBlocks run a tail:
//   tailMode 1: CSR fill (raw src,w — no dinv dependency)
//   tailMode 2: per-vertex no-atomic deg sum over CSR + dinv
__global__ __launch_bounds__(128) void k_gemm_mfma(
    const void* __restrict__ A0, const void* __restrict__ A1,
    const void* __restrict__ A2, const u16* __restrict__ A3,
    const u16* __restrict__ A4, int mode, int K,
    const u16* __restrict__ W, const float* __restrict__ bias,
    void* __restrict__ Cout, int out_bf, int M, const int* __restrict__ flag,
    const int* __restrict__ esrc, const int* __restrict__ edst,
    const void* __restrict__ ew, int* __restrict__ cursor,
    int2* __restrict__ csr, const int* __restrict__ startT,
    float* __restrict__ dinvOut, int tailN, int tailMode, int gemmBlocks) {
  const int isf = flag[0];
  const int tid = threadIdx.x;
  if ((int)blockIdx.x >= gemmBlocks) {
    int i = ((int)blockIdx.x - gemmBlocks) * 128 + tid;
    if (i < tailN) {
      if (tailMode == 1) {
        int s = esrc[i];
        float wv = loadf(ew, i, isf);
        int p = atomicAdd(&cursor[edst[i]], 1);
        csr[p] = make_int2(s, __float_as_int(wv));
      } else {
        int a = startT[i], b = startT[i + 1];
        float sum = 1.f;  // self-loop weight
        for (int k = a; k < b; ++k) sum += __int_as_float(csr[k].y);
        dinvOut[i] = 1.f / sqrtf(sum);
      }
    }
    return;
  }
  const int w = tid >> 6, lane = tid & 63;
  const int l31 = lane & 31, lh = lane >> 5;
  const int w23 = w;                 // column tile (0..1)
  const int mbase = blockIdx.x * 32; // single 32-row tile per block
  const int row = mbase + l31;
  const int rowc = row < M ? row : M - 1;

  f32x16 acc0 = (f32x16)(0.f), acc1 = (f32x16)(0.f);
  const int nk = K >> 4;
  for (int kb = 0; kb < nk; ++kb) {
    bf16x8 a;
    if (mode == 0) {
      a = *(const bf16x8*)((const u16*)A0 + (size_t)rowc * K + kb * 16 + lh * 8);
    } else {
      int r5 = 5 * rowc + (kb >> 3);
      int slot = r5 / NN;
      int inner = r5 - slot * NN;
      int koff = (kb & 7) * 16 + lh * 8;
      if (slot < 3) {
        const void* p = (slot == 0) ? A0 : (slot == 1) ? A1 : A2;
        if (isf) {
          const float* fp = (const float*)p + (size_t)inner * 128 + koff;
          float4 v0 = *(const float4*)fp;
          float4 v1 = *(const float4*)(fp + 4);
          a[0] = (short)f2bf(v0.x); a[1] = (short)f2bf(v0.y);
          a[2] = (short)f2bf(v0.z); a[3] = (short)f2bf(v0.w);
          a[4] = (short)f2bf(v1.x); a[5] = (short)f2bf(v1.y);
          a[6] = (short)f2bf(v1.z); a[7] = (short)f2bf(v1.w);
        } else {
          a = *(const bf16x8*)((const u16*)p + (size_t)inner * 128 + koff);
        }
      } else {
        const u16* p = (slot == 3) ? A3 : A4;
        a = *(const bf16x8*)(p + (size_t)inner * 128 + koff);
      }
    }
    const u16* wp = W + (size_t)(64 * w23 + l31) * K + kb * 16 + lh * 8;
    bf16x8 b0 = *(const bf16x8*)wp;
    bf16x8 b1 = *(const bf16x8*)(wp + (size_t)32 * K);
    acc0 = __builtin_amdgcn_mfma_f32_32x32x16_bf16(a, b0, acc0, 0, 0, 0);
    acc1 = __builtin_amdgcn_mfma_f32_32x32x16_bf16(a, b1, acc1, 0, 0, 0);
  }
  const int col0 = 64 * w23 + l31;
  const float bv0 = bias ? bias[col0] : 0.f;
  const float bv1 = bias ? bias[col0 + 32] : 0.f;
#pragma unroll
  for (int rg = 0; rg < 16; ++rg) {
    int m = (rg & 3) + 8 * (rg >> 2) + 4 * lh;
    int grow = mbase + m;
    if (grow < M) {
      float v0 = acc0[rg] + bv0, v1 = acc1[rg] + bv1;
      if (out_bf) {
        ((u16*)Cout)[(size_t)grow * 128 + col0] = f2bf(v0);
        ((u16*)Cout)[(size_t)grow * 128 + col0 + 32] = f2bf(v1);
      } else {
        ((float*)Cout)[(size_t)grow * 128 + col0] = v0;
        ((float*)Cout)[(size_t)grow * 128 + col0 + 32] = v1;
      }
    }
  }
}

// ------------------------------------------------- fused GCN gather epilogue
// v3: TWO waves per vertex — each wave sums half the edge range (halves the
// serial csr->row dependent chain; kernel is L2-latency-bound, not BW-bound),
// partials combined via LDS; half-0 wave runs the epilogue.
// csr holds raw (src, w); dinv[src] applied per edge (80KB L2-resident).
// mode 1: writes emb chunk to d_out AND computes the collapsed mp head.
__global__ __launch_bounds__(256) void k_gcn_gather(
    const int* __restrict__ start, const int2* __restrict__ csr,
    const float* __restrict__ dinv, const u16* __restrict__ xwbf,
    const float* __restrict__ bias, const float* __restrict__ g,
    const float* __restrict__ b, u16* __restrict__ out_bf,
    void* __restrict__ dout, const float* __restrict__ Wc,
    const int* __restrict__ flag, int mode) {
  __shared__ float part[2][128];
  const int slot = threadIdx.x >> 7;        // vertex slot in block (0..1)
  const int v = blockIdx.x * 2 + slot;      // NN even -> always valid
  const int half = (threadIdx.x >> 6) & 1;  // which wave of the pair
  const int lane = threadIdx.x & 63;
  const int c0 = 2 * lane;
  float acc0 = 0.f, acc1 = 0.f;
  const int i0 = start[v];
  const int i1 = start[v + 1];
  const int mid = i0 + ((i1 - i0) >> 1);
  int i = half ? mid : i0;
  const int hi = half ? i1 : mid;
  for (; i + 4 <= hi; i += 4) {
    int2 e0 = csr[i], e1 = csr[i + 1], e2 = csr[i + 2], e3 = csr[i + 3];
    unsigned p0 = *(const unsigned*)(xwbf + (size_t)e0.x * 128 + c0);
    unsigned p1 = *(const unsigned*)(xwbf + (size_t)e1.x * 128 + c0);
    unsigned p2 = *(const unsigned*)(xwbf + (size_t)e2.x * 128 + c0);
    unsigned p3 = *(const unsigned*)(xwbf + (size_t)e3.x * 128 + c0);
    float f0 = __int_as_float(e0.y) * dinv[e0.x];
    float f1 = __int_as_float(e1.y) * dinv[e1.x];
    float f2 = __int_as_float(e2.y) * dinv[e2.x];
    float f3 = __int_as_float(e3.y) * dinv[e3.x];
    acc0 += f0 * bf2f((u16)(p0 & 0xffff)) + f1 * bf2f((u16)(p1 & 0xffff)) +
            f2 * bf2f((u16)(p2 & 0xffff)) + f3 * bf2f((u16)(p3 & 0xffff));
    acc1 += f0 * bf2f((u16)(p0 >> 16)) + f1 * bf2f((u16)(p1 >> 16)) +
            f2 * bf2f((u16)(p2 >> 16)) + f3 * bf2f((u16)(p3 >> 16));
  }
  if (i + 2 <= hi) {
    int2 e0 = csr[i], e1 = csr[i + 1];
    unsigned p0 = *(const unsigned*)(xwbf + (size_t)e0.x * 128 + c0);
    unsigned p1 = *(const unsigned*)(xwbf + (size_t)e1.x * 128 + c0);
    float f0 = __int_as_float(e0.y) * dinv[e0.x];
    float f1 = __int_as_float(e1.y) * dinv[e1.x];
    acc0 += f0 * bf2f((u16)(p0 & 0xffff)) + f1 * bf2f((u16)(p1 & 0xffff));
    acc1 += f0 * bf2f((u16)(p0 >> 16)) + f1 * bf2f((u16)(p1 >> 16));
    i += 2;
  }
  if (i < hi) {
    int2 e = csr[i];
    float c = __int_as_float(e.y) * dinv[e.x];
    unsigned pv = *(const unsigned*)(xwbf + (size_t)e.x * 128 + c0);
    acc0 += c * bf2f((u16)(pv & 0xffff));
    acc1 += c * bf2f((u16)(pv >> 16));
  }
  if (half) {
    part[slot][c0] = acc0;
    part[slot][c0 + 1] = acc1;
  }
  __syncthreads();   // unconditional: every thread reaches this barrier
  if (half) return;
  acc0 += part[slot][c0];
  acc1 += part[slot][c0 + 1];
  float dv = dinv[v];
  unsigned sv = *(const unsigned*)(xwbf + (size_t)v * 128 + c0);
  float y0 = bias[c0] + dv * (dv * bf2f((u16)(sv & 0xffff)) + acc0);
  float y1 = bias[c0 + 1] + dv * (dv * bf2f((u16)(sv >> 16)) + acc1);
  if (mode == 1) {
    // emb chunk -> d_out directly, in detected dtype
    if (flag[0]) {
      *(float2*)((float*)dout + (size_t)v * 128 + c0) = make_float2(y0, y1);
    } else {
      unsigned pk = (unsigned)f2bf(y0) | ((unsigned)f2bf(y1) << 16);
      *(unsigned*)((u16*)dout + (size_t)v * 128 + c0) = pk;
    }
    // fused mp head on the relu'd row held across the wave
    float x0 = fmaxf(y0, 0.f), x1 = fmaxf(y1, 0.f);
    float p0 = x0 * Wc[c0] + x1 * Wc[c0 + 1];
    float p1 = x0 * Wc[128 + c0] + x1 * Wc[128 + c0 + 1];
#pragma unroll
    for (int off = 32; off; off >>= 1) {
      p0 += __shfl_xor(p0, off);
      p1 += __shfl_xor(p1, off);
    }
    if (lane == 0) {
      float v0 = p0 + Wc[256], v1 = p1 + Wc[257];
      float m = fmaxf(v0, v1);
      float ls = m + logf(__expf(v0 - m) + __expf(v1 - m));
      size_t base = (size_t)NN * 128 + (size_t)v * 2;
      if (flag[0]) {
        ((float*)dout)[base + 0] = v0 - ls;
        ((float*)dout)[base + 1] = v1 - ls;
      } else {
        unsigned pk = (unsigned)f2bf(v0 - ls) | ((unsigned)f2bf(v1 - ls) << 16);
        *(unsigned*)((u16*)dout + base) = pk;
      }
    }
  } else {
    float x0 = fmaxf(y0, 0.f), x1 = fmaxf(y1, 0.f);
    float s_ = x0 + x1;
#pragma unroll
    for (int off = 32; off; off >>= 1) s_ += __shfl_xor(s_, off);
    float mean = s_ * (1.f / 128.f);
    float e0 = x0 - mean, e1 = x1 - mean;
    float vv = e0 * e0 + e1 * e1;
#pragma unroll
    for (int off = 32; off; off >>= 1) vv += __shfl_xor(vv, off);
    float inv = 1.f / sqrtf(vv * (1.f / 128.f) + 1e-5f);
    unsigned pk = (unsigned)f2bf(e0 * inv * g[c0] + b[c0]) |
                  ((unsigned)f2bf(e1 * inv * g[c0 + 1] + b[c0 + 1]) << 16);
    *(unsigned*)(out_bf + (size_t)v * 128 + c0) = pk;
  }
}

// ---------------------------------------------------------------- launch
extern "C" void kernel_launch(void* const* d_in, const int* in_sizes, int n_in,
                              void* d_out, int out_size, void* d_ws, size_t ws_size,
                              hipStream_t stream) {
  const int* idx_lp = (const int*)d_in[0];
  const int* len_lp = (const int*)d_in[1];
  const int* idx_ns = (const int*)d_in[2];
  const int* len_ns = (const int*)d_in[3];
  const void* x_ref = d_in[4];
  const void* x_def = d_in[5];
  const void* x_pdt = d_in[6];
  const int* eidx   = (const int*)d_in[7];
  const void* ew    = d_in[8];
  const void* lp_emb = d_in[9];
  const void* ns_emb = d_in[10];

  // ---- workspace layout ----
  char* cur = (char*)d_ws;
  auto alloc = [&](size_t bytes, size_t align) -> void* {
    size_t a = ((size_t)cur + align - 1) & ~(align - 1);
    cur = (char*)(a + bytes);
    return (void*)a;
  };
  int* flag     = (int*)alloc(64, 64);
  float* smallW = (float*)alloc(3104 * 4, 16);
  float* f_Wc   = (float*)alloc(260 * 4, 16);     // combined mp head [2][128]+bc
  float* f_dinv = (float*)alloc(NN * 4, 16);
  int* counts   = (int*)alloc(NN * 4, 16);
  int* startA   = (int*)alloc((NN + 1) * 4, 16);
  int* cursorE  = (int*)alloc(NN * 4, 16);
  int* bins     = (int*)alloc(128 * 4, 16);
  int* perm_lp  = (int*)alloc(PP * NN * 4, 16);
  int* perm_ns  = (int*)alloc(NN * 4, 16);
  int2* csr2    = (int2*)alloc((size_t)EE * 8, 16);
  u16* ub       = (u16*)alloc((size_t)20233216 * 2, 16);
  u16* embbf_lp = ub;
  u16* embbf_ns = ub + 640000;
  u16* wg_lpih  = ub + 1920000;
  u16* wg_lphh  = ub + 1969152;
  u16* wg_nsih  = ub + 2018304;
  u16* wg_nshh  = ub + 2067456;
  u16* wg_lpfc  = ub + 2116608;
  u16* wg_allfc = ub + 2165760;
  u16* wg_c1    = ub + 2247680;
  u16* wg_c2    = ub + 2264064;
  u16* wg_c3    = ub + 2280448;
  u16* hbf_lp   = ub + 2313216;   // [3N,128]
  u16* hbf_ns   = ub + 9993216;   // [N,128]
  u16* lp_bf    = ub + 12553216;  // [N,128]
  u16* xcur_bf  = ub + 15113216;  // [N,128]
  u16* xw_bf    = ub + 17673216;  // [N,128]

  static const int fn[16] = {384, 384, 384, 384, 128, 128, 128, 128,
                             128, 128, 128, 128, 128, 128, 256, 2};
  static const int fsrc[16] = {13, 14, 17, 18, 20, 22, 24, 26,
                               28, 29, 30, 31, 32, 34, 35, 36};
  CvtJobs jf;
  int foff[16];
  {
    int off = 0;
    for (int j = 0; j < 16; ++j) {
      jf.src[j] = d_in[fsrc[j]];
      jf.off[j] = off;
      jf.n[j] = fn[j];
      foff[j] = off;
      off += fn[j];
    }
  }
  float* b_lpbih = smallW + foff[0];
  float* b_lpbhh = smallW + foff[1];
  float* b_nsbih = smallW + foff[2];
  float* b_nsbhh = smallW + foff[3];
  float* b_lpfc  = smallW + foff[4];
  float* b_allfc = smallW + foff[5];
  float* b_conv[3] = {smallW + foff[6], smallW + foff[7], smallW + foff[8]};
  float* g_ln[2] = {smallW + foff[9], smallW + foff[11]};
  float* b_ln[2] = {smallW + foff[10], smallW + foff[12]};
  float* b_mp1   = smallW + foff[13];
  float* w_mp2   = smallW + foff[14];
  float* b_mp2   = smallW + foff[15];

  // job 11 (mp1 weight) removed — its consumer (mp1 GEMM) was collapsed
  static const int bn[12] = {640000, 1280000, 49152, 49152, 49152, 49152,
                             49152, 81920, 16384, 16384, 16384, 0};
  static const int bsrc[12] = {9, 10, 11, 12, 15, 16, 19, 21, 23, 25, 27, 33};
  static const int boff[12] = {0, 640000, 1920000, 1969152, 2018304, 2067456,
                               2116608, 2165760, 2247680, 2264064, 2280448,
                               2296832};
  CvtJobsB jb;
  for (int j = 0; j < 12; ++j) {
    jb.src[j] = d_in[bsrc[j]];
    jb.off[j] = boff[j];
    jb.n[j] = bn[j];
    // jobs 2..5 are the GRU weight matrices [3*128 x 128]:
    // pre-scale r,z gate rows (first 32768 elems) by -log2e, n rows by -2log2e
    const bool gw = (j >= 2 && j <= 5);
    jb.thr[j] = gw ? 32768 : 0;
    jb.scA[j] = gw ? -1.44269504088896f : 1.f;
    jb.scB[j] = gw ? -2.88539008177793f : 1.f;
  }

  const int* e_src = eidx;
  const int* e_dst = eidx + EE;

  // 0. dtype detection (+ bins zero)
  k_detect<<<1, 256, 0, stream>>>(lp_emb, flag, bins);

  // 1. conversions (bf16 jobs + float jobs + counts zero, one launch)
  const int initBlocks = (NN + 255) / 256;
  k_cvtb<<<12 * 64 + 16 + initBlocks, 256, 0, stream>>>(jb, jf, ub, smallW,
                                                        counts, flag);

  // 2. length hist (merged LP+NS) + edge hist in tail blocks
  const int lenBlocks = (PP * NN + 255) / 256;
  const int histBlocks = (EE + 255) / 256;
  k_lenboth<<<lenBlocks + histBlocks, 256, 0, stream>>>(len_lp, len_ns, bins,
                                                        e_dst, counts);
  k_binscan2<<<2, 256, 0, stream>>>(bins, w_mp2, b_mp1, b_mp2, d_in[33],
                                    f_Wc, flag);
  k_lenfillboth<<<lenBlocks, 256, 0, stream>>>(len_lp, len_ns, bins,
                                               perm_lp, perm_ns);

  // 3. merged GRUs (block 0 = CSR offset scan, hidden under gru)
  const int nbLP = PP * NN / 32, nbNS = NN / 32;
  k_gru5<<<1 + nbLP + nbNS, 512, 0, stream>>>(
      perm_lp, perm_ns, nbNS, embbf_lp, embbf_ns,
      (const u16*)lp_emb, (const u16*)ns_emb,
      idx_lp, idx_ns, len_lp, len_ns,
      wg_lpih, wg_lphh, wg_nsih, wg_nshh, b_lpbih, b_lpbhh, b_nsbih, b_nsbhh,
      hbf_lp, hbf_ns, nbLP, counts, startA, cursorE, flag);

  const int gg = (NN + 31) / 32;  // 32-row tiles, 128-thr blocks
  const int fillBlocks = (EE + 127) / 128;
  const int degBlocks = (NN + 127) / 128;
  // 4. lp_fc GEMM (+ raw CSR fill in tail; csr not read until all_fc tail)
  k_gemm_mfma<<<gg + fillBlocks, 128, 0, stream>>>(
      hbf_lp, nullptr, nullptr, nullptr, nullptr, 0, 384, wg_lpfc, b_lpfc,
      lp_bf, 1, NN, flag, e_src, e_dst, ew, cursorE, csr2, nullptr, nullptr,
      EE, 1, gg);
  // 5. all_fc GEMM (+ no-atomic deg-sum/dinv in tail; dinv not read until gather)
  k_gemm_mfma<<<gg + degBlocks, 128, 0, stream>>>(
      x_pdt, x_ref, x_def, lp_bf, hbf_ns, 1, 640, wg_allfc, b_allfc,
      xcur_bf, 1, NN, flag, nullptr, nullptr, nullptr, nullptr, csr2, startA,
      f_dinv, NN, 2, gg);

  // 6. three GCN layers (last gather fuses emb-out + mp head)
  const u16* wgc[3] = {wg_c1, wg_c2, wg_c3};
  for (int l = 0; l < 3; ++l) {
    k_gemm_mfma<<<gg, 128, 0, stream>>>(
        xcur_bf, nullptr, nullptr, nullptr, nullptr, 0, DD, wgc[l], nullptr,
        xw_bf, 1, NN, flag, nullptr, nullptr, nullptr, nullptr, nullptr,
        nullptr, nullptr, 0, 0, gg);
    if (l < 2) {
      k_gcn_gather<<<NN / 2, 256, 0, stream>>>(startA, csr2, f_dinv, xw_bf,
                                               b_conv[l], g_ln[l], b_ln[l],
                                               xcur_bf, nullptr, nullptr,
                                               flag, 0);
    } else {
      k_gcn_gather<<<NN / 2, 256, 0, stream>>>(startA, csr2, f_dinv, xw_bf,
                                               b_conv[l], nullptr, nullptr,
                                               nullptr, d_out, f_Wc,
                                               flag, 1);
    }
  }
}

// Round 12
// 822.963 us; speedup vs baseline: 1.0313x; 1.0313x over previous
//
#include <hip/hip_runtime.h>
#include <math.h>

typedef unsigned short u16;
typedef short bf16x4 __attribute__((ext_vector_type(4)));
typedef short bf16x8 __attribute__((ext_vector_type(8)));
typedef float f32x16 __attribute__((ext_vector_type(16)));

#define NN 20000
#define PP 3
#define TLP 10
#define TNS 20
#define DD 128
#define EE 640000

__device__ __forceinline__ float bf2f(u16 u) {
  union { unsigned u; float f; } v; v.u = ((unsigned)u) << 16; return v.f;
}
__device__ __forceinline__ u16 f2bf(float f) {
  union { float f; unsigned u; } v; v.f = f;
  unsigned r = v.u + 0x7fffu + ((v.u >> 16) & 1u);
  return (u16)(r >> 16);
}
// HW bf16 convert via compiler-visible fptrunc (RNE, hazard-managed).
// Safe on MFMA accumulator reads (unlike inline-asm cvtpk).
__device__ __forceinline__ short f2bf_hw(float f) {
  __bf16 b = (__bf16)f;
  return (short)__builtin_bit_cast(unsigned short, b);
}
__device__ __forceinline__ float loadf(const void* p, size_t i, int isf) {
  return isf ? ((const float*)p)[i] : bf2f(((const u16*)p)[i]);
}
// exp2-domain transcendentals via intrinsics (hazards compiler-managed)
__device__ __forceinline__ float fex2(float x) { return __builtin_amdgcn_exp2f(x); }
__device__ __forceinline__ float frcp(float x) { return __builtin_amdgcn_rcpf(x); }
// packed bf16 convert — ONLY on plain-VALU-produced values (m214-proven).
// NEVER on direct MFMA accumulator reads (R1/R2 corruption: asm consumer of
// MFMA dst misses mandatory wait-states).
__device__ __forceinline__ unsigned cvtpk(float lo, float hi) {
  unsigned r; asm("v_cvt_pk_bf16_f32 %0, %1, %2" : "=v"(r) : "v"(lo), "v"(hi));
  return r;
}

// ------------------------------------------------------------- dtype detect
// block 0: probe + zero bins (incl. the zero-based fill cursors);
// blocks 1..: zero counts (moved here so the edge hist can fuse into megacvt)
__global__ void k_detect(const void* probe, int* flag, int* bins,
                         int* __restrict__ counts) {
  if (blockIdx.x > 0) {
    int i = (blockIdx.x - 1) * 256 + threadIdx.x;
    if (i < NN) counts[i] = 0;
    return;
  }
  __shared__ int any;
  if (threadIdx.x == 0) any = 0;
  __syncthreads();
  if (threadIdx.x < 128) bins[threadIdx.x] = 0;
  const u16* p = (const u16*)probe;
  int bad = 0;
  for (int i = threadIdx.x; i < 4096; i += 256) {
    int e = (p[2 * i] >> 7) & 0xFF;
    if (e >= 0x9F) bad = 1;
  }
  if (bad) atomicOr(&any, 1);
  __syncthreads();
  if (threadIdx.x == 0) flag[0] = any;  // 1 = f32, 0 = bf16
}

// ------------------------------------------------------------- converters
struct CvtJobs {
  const void* src[16];
  int off[16];
  int n[16];
};

struct CvtJobsB {
  const void* src[12];
  int off[12];
  int n[12];
  int thr[12];     // i < thr -> scA else scB
  float scA[12];
  float scB[12];
};

// mega-launch: [0,768) bf16 jobs; [768,784) float jobs; then LP+NS length
// hist; then counts-only edge hist; last block computes the collapsed
// mp-head weights Wc from RAW inputs (no smallW dependency):
//   Wc[o][k] = sum_d mp2[o][d]*mp1[d][k]; bc[o] = mp2[o]·b_mp1 + b_mp2[o]
// All sections are mutually independent -> one launch, full overlap.
__global__ void k_megacvt(CvtJobsB j, CvtJobs jf, u16* __restrict__ dst,
                          float* __restrict__ fdst,
                          const int* __restrict__ lensLP,
                          const int* __restrict__ lensNS,
                          int* __restrict__ bins,
                          const int* __restrict__ e_dst,
                          int* __restrict__ counts,
                          const void* __restrict__ w2raw,
                          const void* __restrict__ b1raw,
                          const void* __restrict__ b2raw,
                          const void* __restrict__ mp1raw,
                          float* __restrict__ Wc, const int* flag) {
  const int isf = flag[0];
  const int B_CVT = 12 * 64;
  const int B_F = B_CVT + 16;
  const int LEN_B = (PP * NN + 255) / 256;
  const int B_LEN = B_F + LEN_B;
  const int HIST_B = (EE + 255) / 256;
  const int B_HIST = B_LEN + HIST_B;
  const int bx = (int)blockIdx.x;
  const int tid = threadIdx.x;
  if (bx < B_CVT) {
    const int job = bx >> 6;
    if (job < 2 && !isf) return;  // bf16 input: embeddings used in place
    const int chunk = bx & 63;
    const void* s = j.src[job];
    u16* d = dst + j.off[job];
    const int n = j.n[job];
    const int thr = j.thr[job];
    const float sA = j.scA[job], sB = j.scB[job];
    for (int i = chunk * 256 + tid; i < n; i += 64 * 256)
      d[i] = f2bf(loadf(s, i, isf) * (i < thr ? sA : sB));
    return;
  }
  if (bx < B_F) {
    const int job = bx - B_CVT;
    const void* s = jf.src[job];
    float* d = fdst + jf.off[job];
    const int n = jf.n[job];
    for (int i = tid; i < n; i += 256) d[i] = loadf(s, i, isf);
    return;
  }
  if (bx < B_LEN) {
    int sg = (bx - B_F) * 256 + tid;
    int lane = tid & 63;
    int binL = 0, binN = 0;
    if (sg < PP * NN) binL = lensLP[(sg % NN) * PP + sg / NN];
    if (sg < NN) binN = lensNS[sg];
    for (int b = 1; b <= TLP; ++b) {
      unsigned long long m = __ballot(binL == b);
      if (m) {
        int leader = (int)(__ffsll((long long)m) - 1);
        if (lane == leader) atomicAdd(&bins[b], (int)__popcll(m));
      }
    }
    for (int b = 1; b <= TNS; ++b) {
      unsigned long long m = __ballot(binN == b);
      if (m) {
        int leader = (int)(__ffsll((long long)m) - 1);
        if (lane == leader) atomicAdd(&bins[64 + b], (int)__popcll(m));
      }
    }
    return;
  }
  if (bx < B_HIST) {
    int e = (bx - B_LEN) * 256 + tid;
    if (e < EE) atomicAdd(&counts[e_dst[e]], 1);
    return;
  }
  // last block: combined mp-head weights from raw inputs
  const int o = tid >> 7, k = tid & 127;
  float acc = 0.f;
  for (int d2 = 0; d2 < 128; ++d2)
    acc += loadf(w2raw, o * 128 + d2, isf) * loadf(mp1raw, (size_t)d2 * 128 + k, isf);
  Wc[tid] = acc;
  if (tid < 2) {
    float bacc = loadf(b2raw, tid, isf);
    for (int d2 = 0; d2 < 128; ++d2)
      bacc += loadf(w2raw, tid * 128 + d2, isf) * loadf(b1raw, d2, isf);
    Wc[256 + tid] = bacc;
  }
}

// ------------------------------------------------------------- length fill
// counting-sort placement; the 32-bin exclusive scan is computed LOCALLY per
// block (bins counts finalized in megacvt); bins[32+b]/bins[96+b] are plain
// zero-based atomic cursors (zeroed in detect). Placement math identical to
// the old binscan2+fill pair.
__global__ void k_lenfillboth(const int* __restrict__ lensLP,
                              const int* __restrict__ lensNS,
                              int* __restrict__ bins,
                              int* __restrict__ permLP,
                              int* __restrict__ permNS) {
  int sg = blockIdx.x * 256 + threadIdx.x;
  int lane = threadIdx.x & 63;
  int binL = 0, binN = 0;
  if (sg < PP * NN) binL = lensLP[(sg % NN) * PP + sg / NN];
  if (sg < NN) binN = lensNS[sg];
  int baseL = 0;
  for (int b = 1; b <= TLP; ++b) {
    unsigned long long m = __ballot(binL == b);
    if (m) {
      int leader = (int)(__ffsll((long long)m) - 1);
      int base = 0;
      if (lane == leader) base = atomicAdd(&bins[32 + b], (int)__popcll(m));
      base = __shfl(base, leader);
      if (binL == b) {
        int rank = (int)__popcll(m & ((1ull << lane) - 1ull));
        permLP[baseL + base + rank] = sg;
      }
    }
    baseL += bins[b];
  }
  int baseN = 0;
  for (int b = 1; b <= TNS; ++b) {
    unsigned long long m = __ballot(binN == b);
    if (m) {
      int leader = (int)(__ffsll((long long)m) - 1);
      int base = 0;
      if (lane == leader) base = atomicAdd(&bins[96 + b], (int)__popcll(m));
      base = __shfl(base, leader);
      if (binN == b) {
        int rank = (int)__popcll(m & ((1ull << lane) - 1ull));
        permNS[baseN + base + rank] = sg;
      }
    }
    baseN += bins[64 + b];
  }
}

// ---------------------------------------------------------------- GRU v13
// gru body unchanged (control). Block 0 runs the CSR offset scan (hist
// completed in megacvt; scan output first read in lp_fc's fill tail).
__global__ __launch_bounds__(512, 2) void k_gru5(
    const int* __restrict__ permLP, const int* __restrict__ permNS, int nbNS,
    const u16* __restrict__ embLPc, const u16* __restrict__ embNSc,
    const u16* __restrict__ embLPr, const u16* __restrict__ embNSr,
    const int* __restrict__ idxLP, const int* __restrict__ idxNS,
    const int* __restrict__ lenLP, const int* __restrict__ lenNS,
    const u16* __restrict__ WihLP, const u16* __restrict__ WhhLP,
    const u16* __restrict__ WihNS, const u16* __restrict__ WhhNS,
    const float* __restrict__ bihLP, const float* __restrict__ bhhLP,
    const float* __restrict__ bihNS, const float* __restrict__ bhhNS,
    u16* __restrict__ HoutLP, u16* __restrict__ HoutNS, int nbLP,
    const int* __restrict__ counts, int* __restrict__ startA,
    int* __restrict__ cursorE, const int* __restrict__ flag) {
  __shared__ u16 xp[2][3][128][36];   // [slot][gate][d][m] bf16, b64-packed
  __shared__ u16 Hbf2[2][32][132];    // [slot][m][d], pad 132
  __shared__ int ivs[TNS][32];
  __shared__ int rowv[32], outv[32], lenv_s[32];
  __shared__ int Tbs;

  const int tid = threadIdx.x;
  if (blockIdx.x == 0) {
    // CSR offset scan (single block; all 512 threads hit both barriers)
    int* part = (int*)ivs;  // 256-int scratch
    const int C = (NN + 255) / 256;
    if (tid < 256) {
      int base = tid * C;
      int s = 0;
      for (int k = 0; k < C; ++k) {
        int i2 = base + k;
        s += (i2 < NN) ? counts[i2] : 0;
      }
      part[tid] = s;
    }
    __syncthreads();
    if (tid == 0) {
      int acc = 0;
      for (int k = 0; k < 256; ++k) { int v = part[k]; part[k] = acc; acc += v; }
    }
    __syncthreads();
    if (tid < 256) {
      int run = part[tid];
      int base = tid * C;
      for (int k = 0; k < C; ++k) {
        int i2 = base + k;
        if (i2 < NN) {
          int c = counts[i2];
          startA[i2] = run;
          cursorE[i2] = run;
          run += c;
        }
      }
      if (tid == 255) startA[NN] = run;
    }
    return;
  }
  const int bid = blockIdx.x - 1;
  const int isf = flag[0];
  const int isNS = bid < nbNS;
  // longest-first: NS family first, descending within each family
  const int chunk = isNS ? (nbNS - 1 - bid) : (nbLP - 1 - (bid - nbNS));
  const int* perm = isNS ? (permNS + chunk * 32) : (permLP + chunk * 32);
  // bf16 input: embeddings used directly from d_in (identity copy skipped)
  const u16* embbf = isNS ? (isf ? embNSc : embNSr) : (isf ? embLPc : embLPr);
  const int* idx = isNS ? idxNS : idxLP;
  const int* lens = isNS ? lenNS : lenLP;
  const u16* Wih = isNS ? WihNS : WihLP;
  const u16* Whh = isNS ? WhhNS : WhhLP;
  const float* bih = isNS ? bihNS : bihLP;
  const float* bhh = isNS ? bhhNS : bhhLP;
  u16* Hout = isNS ? HoutNS : HoutLP;
  const int T = isNS ? TNS : TLP;

  const int w = tid >> 6, lane = tid & 63;
  const int l31 = lane & 31, lh = lane >> 5;
  const int role = w >> 2;  // 0 = X producer, 1 = H consumer
  const int j = w & 3;
  const int d = 32 * j + l31;

  if (tid < 32) {
    int sg = perm[tid];
    int row = isNS ? sg : ((sg % NN) * PP + sg / NN);
    rowv[tid] = row;
    outv[tid] = sg;
    lenv_s[tid] = lens[row];
  }
  __syncthreads();
  if (tid == 0) {
    int m = 1;
    for (int k = 0; k < 32; ++k) m = max(m, lenv_s[k]);
    Tbs = m;
  }
  __syncthreads();
  const int Tb = Tbs;

  for (int z = tid; z < Tb * 32; z += 512) {
    int s = z & 31, t = z >> 5;
    ivs[t][s] = idx[(size_t)rowv[s] * T + t];
  }
  // zero Hbf2 slot 0 (32*132 u16 = 4224 elems = 2112 u32)
  for (int z = tid; z < 2112; z += 512) ((unsigned*)Hbf2[0])[z] = 0u;

  bf16x8 wf[24];
  {
    const u16* Ws = role ? Whh : Wih;
#pragma unroll
    for (int g = 0; g < 3; ++g)
#pragma unroll
      for (int kb = 0; kb < 8; ++kb)
        wf[g * 8 + kb] =
            *(const bf16x8*)(Ws + (size_t)(128 * g + d) * 128 + kb * 16 + lh * 8);
  }
  // exp2-domain bias folding into accumulator inits:
  //  X waves: a0 += SA*(bir+bhr), a1 += SA*(biz+bhz), a2 += SN*bin
  //  H waves: a2 += SN*bhn  (stays inside the r* multiply)
  const float SA = -1.44269504088896f;   // -log2(e)
  const float SN = -2.88539008177793f;   // -2*log2(e)
  float ib0, ib1, ib2;
  if (!role) {
    ib0 = SA * (bih[d] + bhh[d]);
    ib1 = SA * (bih[128 + d] + bhh[128 + d]);
    ib2 = SN * bih[256 + d];
  } else {
    ib0 = 0.f;
    ib1 = 0.f;
    ib2 = SN * bhh[256 + d];
  }

  __syncthreads();
  int lenr[16];
#pragma unroll
  for (int rg = 0; rg < 16; ++rg)
    lenr[rg] = lenv_s[(rg & 3) + 8 * (rg >> 2) + 4 * lh];

  float h[16];
#pragma unroll
  for (int rg = 0; rg < 16; ++rg) h[rg] = 0.f;

  for (int i = 0; i <= Tb; ++i) {
    if (!role) {
      if (i < Tb) {
        bf16x8 Xf[8];
        const u16* erow = embbf + (size_t)ivs[i][l31] * 128 + lh * 8;
#pragma unroll
        for (int kb = 0; kb < 8; ++kb) Xf[kb] = *(const bf16x8*)(erow + kb * 16);
        f32x16 a0 = (f32x16)(ib0), a1 = (f32x16)(ib1), a2 = (f32x16)(ib2);
#pragma unroll
        for (int kb = 0; kb < 8; ++kb) {
          a0 = __builtin_amdgcn_mfma_f32_32x32x16_bf16(Xf[kb], wf[kb], a0, 0, 0, 0);
          a1 = __builtin_amdgcn_mfma_f32_32x32x16_bf16(Xf[kb], wf[8 + kb], a1, 0, 0, 0);
          a2 = __builtin_amdgcn_mfma_f32_32x32x16_bf16(Xf[kb], wf[16 + kb], a2, 0, 0, 0);
        }
        const int sl = i & 1;
        // packed b64 writes: quad rq -> m base 8rq+4lh (4 consecutive m)
        // MFMA acc reads via compiler-visible HW bf16 cast (hazard-safe)
#pragma unroll
        for (int rq = 0; rq < 4; ++rq) {
          int mo = 8 * rq + 4 * lh;
          bf16x4 p0, p1, p2;
#pragma unroll
          for (int q = 0; q < 4; ++q) {
            p0[q] = f2bf_hw(a0[4 * rq + q]);
            p1[q] = f2bf_hw(a1[4 * rq + q]);
            p2[q] = f2bf_hw(a2[4 * rq + q]);
          }
          *(bf16x4*)(&xp[sl][0][d][mo]) = p0;
          *(bf16x4*)(&xp[sl][1][d][mo]) = p1;
          *(bf16x4*)(&xp[sl][2][d][mo]) = p2;
        }
      }
    } else {
      if (i >= 1) {
        const int rs = (i - 1) & 1, wsl = i & 1;
        bf16x8 Hf[8];
#pragma unroll
        for (int kb = 0; kb < 8; ++kb) {
          bf16x4 lo = *(const bf16x4*)(&Hbf2[rs][l31][16 * kb + 8 * lh]);
          bf16x4 hi = *(const bf16x4*)(&Hbf2[rs][l31][16 * kb + 8 * lh + 4]);
          Hf[kb] = __builtin_shufflevector(lo, hi, 0, 1, 2, 3, 4, 5, 6, 7);
        }
        f32x16 a0 = (f32x16)(ib0), a1 = (f32x16)(ib1), a2 = (f32x16)(ib2);
#pragma unroll
        for (int kb = 0; kb < 8; ++kb) {
          a0 = __builtin_amdgcn_mfma_f32_32x32x16_bf16(Hf[kb], wf[kb], a0, 0, 0, 0);
          a1 = __builtin_amdgcn_mfma_f32_32x32x16_bf16(Hf[kb], wf[8 + kb], a1, 0, 0, 0);
          a2 = __builtin_amdgcn_mfma_f32_32x32x16_bf16(Hf[kb], wf[16 + kb], a2, 0, 0, 0);
        }
        const int t = i - 1;
#pragma unroll
        for (int rq = 0; rq < 4; ++rq) {
          int mo = 8 * rq + 4 * lh;
          bf16x4 x0 = *(const bf16x4*)(&xp[rs][0][d][mo]);
          bf16x4 x1 = *(const bf16x4*)(&xp[rs][1][d][mo]);
          bf16x4 x2 = *(const bf16x4*)(&xp[rs][2][d][mo]);
          float hq[4];
#pragma unroll
          for (int q = 0; q < 4; ++q) {
            int rg = 4 * rq + q;
            // operands in -log2e scaled domain:
            //   sigma(pre) = rcp(1 + 2^(SA*pre)), tanh(y) = 2*rcp(1+2^(SN*y)) - 1
            float r = frcp(1.f + fex2(a0[rg] + bf2f((u16)x0[q])));
            float z = frcp(1.f + fex2(a1[rg] + bf2f((u16)x1[q])));
            float s = fmaf(r, a2[rg], bf2f((u16)x2[q]));
            float nn_ = fmaf(2.f, frcp(1.f + fex2(s)), -1.f);
            float hnew = fmaf(z, h[rg] - nn_, nn_);
            h[rg] = (t < lenr[rg]) ? hnew : h[rg];  // pack_padded mask
            hq[q] = h[rg];
          }
          // cvtpk on plain VALU values (cndmask outputs) — proven-safe
          unsigned pa = cvtpk(hq[0], hq[1]);
          unsigned pb = cvtpk(hq[2], hq[3]);
          Hbf2[wsl][mo + 0][d] = (u16)pa;
          Hbf2[wsl][mo + 1][d] = (u16)(pa >> 16);
          Hbf2[wsl][mo + 2][d] = (u16)pb;
          Hbf2[wsl][mo + 3][d] = (u16)(pb >> 16);
        }
      }
    }
    __syncthreads();
  }

  if (role) {
#pragma unroll
    for (int rg = 0; rg < 16; ++rg) {
      int m = (rg & 3) + 8 * (rg >> 2) + 4 * lh;
      Hout[(size_t)outv[m] * 128 + d] = f2bf(h[rg]);
    }
  }
}

// ---------------------------------------------------------------- GEMM (MFMA, LDS-free)
// 128-thr blocks, 32-row tiles. blocks >= gemmBlocks run a tail:
//   tailMode 1: CSR fill (raw src,w — no dinv dependency)
//   tailMode 2: per-vertex no-atomic deg sum over CSR + dinv
__global__ __launch_bounds__(128) void k_gemm_mfma(
    const void* __restrict__ A0, const void* __restrict__ A1,
    const void* __restrict__ A2, const u16* __restrict__ A3,
    const u16* __restrict__ A4, int mode, int K,
    const u16* __restrict__ W, const float* __restrict__ bias,
    void* __restrict__ Cout, int out_bf, int M, const int* __restrict__ flag,
    const int* __restrict__ esrc, const int* __restrict__ edst,
    const void* __restrict__ ew, int* __restrict__ cursor,
    int2* __restrict__ csr, const int* __restrict__ startT,
    float* __restrict__ dinvOut, int tailN, int tailMode, int gemmBlocks) {
  const int isf = flag[0];
  const int tid = threadIdx.x;
  if ((int)blockIdx.x >= gemmBlocks) {
    int i = ((int)blockIdx.x - gemmBlocks) * 128 + tid;
    if (i < tailN) {
      if (tailMode == 1) {
        int s = esrc[i];
        float wv = loadf(ew, i, isf);
        int p = atomicAdd(&cursor[edst[i]], 1);
        csr[p] = make_int2(s, __float_as_int(wv));
      } else {
        int a = startT[i], b = startT[i + 1];
        float sum = 1.f;  // self-loop weight
        for (int k = a; k < b; ++k) sum += __int_as_float(csr[k].y);
        dinvOut[i] = 1.f / sqrtf(sum);
      }
    }
    return;
  }
  const int w = tid >> 6, lane = tid & 63;
  const int l31 = lane & 31, lh = lane >> 5;
  const int w23 = w;                 // column tile (0..1)
  const int mbase = blockIdx.x * 32; // single 32-row tile per block
  const int row = mbase + l31;
  const int rowc = row < M ? row : M - 1;

  f32x16 acc0 = (f32x16)(0.f), acc1 = (f32x16)(0.f);
  const int nk = K >> 4;
  for (int kb = 0; kb < nk; ++kb) {
    bf16x8 a;
    if (mode == 0) {
      a = *(const bf16x8*)((const u16*)A0 + (size_t)rowc * K + kb * 16 + lh * 8);
    } else {
      int r5 = 5 * rowc + (kb >> 3);
      int slot = r5 / NN;
      int inner = r5 - slot * NN;
      int koff = (kb & 7) * 16 + lh * 8;
      if (slot < 3) {
        const void* p = (slot == 0) ? A0 : (slot == 1) ? A1 : A2;
        if (isf) {
          const float* fp = (const float*)p + (size_t)inner * 128 + koff;
          float4 v0 = *(const float4*)fp;
          float4 v1 = *(const float4*)(fp + 4);
          a[0] = (short)f2bf(v0.x); a[1] = (short)f2bf(v0.y);
          a[2] = (short)f2bf(v0.z); a[3] = (short)f2bf(v0.w);
          a[4] = (short)f2bf(v1.x); a[5] = (short)f2bf(v1.y);
          a[6] = (short)f2bf(v1.z); a[7] = (short)f2bf(v1.w);
        } else {
          a = *(const bf16x8*)((const u16*)p + (size_t)inner * 128 + koff);
        }
      } else {
        const u16* p = (slot == 3) ? A3 : A4;
        a = *(const bf16x8*)(p + (size_t)inner * 128 + koff);
      }
    }
    const u16* wp = W + (size_t)(64 * w23 + l31) * K + kb * 16 + lh * 8;
    bf16x8 b0 = *(const bf16x8*)wp;
    bf16x8 b1 = *(const bf16x8*)(wp + (size_t)32 * K);
    acc0 = __builtin_amdgcn_mfma_f32_32x32x16_bf16(a, b0, acc0, 0, 0, 0);
    acc1 = __builtin_amdgcn_mfma_f32_32x32x16_bf16(a, b1, acc1, 0, 0, 0);
  }
  const int col0 = 64 * w23 + l31;
  const float bv0 = bias ? bias[col0] : 0.f;
  const float bv1 = bias ? bias[col0 + 32] : 0.f;
#pragma unroll
  for (int rg = 0; rg < 16; ++rg) {
    int m = (rg & 3) + 8 * (rg >> 2) + 4 * lh;
    int grow = mbase + m;
    if (grow < M) {
      float v0 = acc0[rg] + bv0, v1 = acc1[rg] + bv1;
      if (out_bf) {
        ((u16*)Cout)[(size_t)grow * 128 + col0] = f2bf(v0);
        ((u16*)Cout)[(size_t)grow * 128 + col0 + 32] = f2bf(v1);
      } else {
        ((float*)Cout)[(size_t)grow * 128 + col0] = v0;
        ((float*)Cout)[(size_t)grow * 128 + col0 + 32] = v1;
      }
    }
  }
}

// ------------------------------------------------- fused GCN gather epilogue
// (R10's measured-best 1-wave-per-vertex form; R11's 2-wave split was neutral)
// csr holds raw (src, w); dinv[src] applied per edge (80KB L2-resident).
// mode 1: writes emb chunk to d_out AND computes the collapsed mp head.
__global__ __launch_bounds__(256) void k_gcn_gather(
    const int* __restrict__ start, const int2* __restrict__ csr,
    const float* __restrict__ dinv, const u16* __restrict__ xwbf,
    const float* __restrict__ bias, const float* __restrict__ g,
    const float* __restrict__ b, u16* __restrict__ out_bf,
    void* __restrict__ dout, const float* __restrict__ Wc,
    const int* __restrict__ flag, int mode) {
  int v = blockIdx.x * 4 + (threadIdx.x >> 6);
  int lane = threadIdx.x & 63;
  if (v >= NN) return;
  const int c0 = 2 * lane;
  float acc0 = 0.f, acc1 = 0.f;
  int i = start[v];
  const int i1 = start[v + 1];
  for (; i + 4 <= i1; i += 4) {
    int2 e0 = csr[i], e1 = csr[i + 1], e2 = csr[i + 2], e3 = csr[i + 3];
    unsigned p0 = *(const unsigned*)(xwbf + (size_t)e0.x * 128 + c0);
    unsigned p1 = *(const unsigned*)(xwbf + (size_t)e1.x * 128 + c0);
    unsigned p2 = *(const unsigned*)(xwbf + (size_t)e2.x * 128 + c0);
    unsigned p3 = *(const unsigned*)(xwbf + (size_t)e3.x * 128 + c0);
    float f0 = __int_as_float(e0.y) * dinv[e0.x];
    float f1 = __int_as_float(e1.y) * dinv[e1.x];
    float f2 = __int_as_float(e2.y) * dinv[e2.x];
    float f3 = __int_as_float(e3.y) * dinv[e3.x];
    acc0 += f0 * bf2f((u16)(p0 & 0xffff)) + f1 * bf2f((u16)(p1 & 0xffff)) +
            f2 * bf2f((u16)(p2 & 0xffff)) + f3 * bf2f((u16)(p3 & 0xffff));
    acc1 += f0 * bf2f((u16)(p0 >> 16)) + f1 * bf2f((u16)(p1 >> 16)) +
            f2 * bf2f((u16)(p2 >> 16)) + f3 * bf2f((u16)(p3 >> 16));
  }
  if (i + 2 <= i1) {
    int2 e0 = csr[i], e1 = csr[i + 1];
    unsigned p0 = *(const unsigned*)(xwbf + (size_t)e0.x * 128 + c0);
    unsigned p1 = *(const unsigned*)(xwbf + (size_t)e1.x * 128 + c0);
    float f0 = __int_as_float(e0.y) * dinv[e0.x];
    float f1 = __int_as_float(e1.y) * dinv[e1.x];
    acc0 += f0 * bf2f((u16)(p0 & 0xffff)) + f1 * bf2f((u16)(p1 & 0xffff));
    acc1 += f0 * bf2f((u16)(p0 >> 16)) + f1 * bf2f((u16)(p1 >> 16));
    i += 2;
  }
  if (i < i1) {
    int2 e = csr[i];
    float c = __int_as_float(e.y) * dinv[e.x];
    unsigned pv = *(const unsigned*)(xwbf + (size_t)e.x * 128 + c0);
    acc0 += c * bf2f((u16)(pv & 0xffff));
    acc1 += c * bf2f((u16)(pv >> 16));
  }
  float dv = dinv[v];
  unsigned sv = *(const unsigned*)(xwbf + (size_t)v * 128 + c0);
  float y0 = bias[c0] + dv * (dv * bf2f((u16)(sv & 0xffff)) + acc0);
  float y1 = bias[c0 + 1] + dv * (dv * bf2f((u16)(sv >> 16)) + acc1);
  if (mode == 1) {
    // emb chunk -> d_out directly, in detected dtype
    if (flag[0]) {
      *(float2*)((float*)dout + (size_t)v * 128 + c0) = make_float2(y0, y1);
    } else {
      unsigned pk = (unsigned)f2bf(y0) | ((unsigned)f2bf(y1) << 16);
      *(unsigned*)((u16*)dout + (size_t)v * 128 + c0) = pk;
    }
    // fused mp head on the relu'd row held across the wave
    float x0 = fmaxf(y0, 0.f), x1 = fmaxf(y1, 0.f);
    float p0 = x0 * Wc[c0] + x1 * Wc[c0 + 1];
    float p1 = x0 * Wc[128 + c0] + x1 * Wc[128 + c0 + 1];
#pragma unroll
    for (int off = 32; off; off >>= 1) {
      p0 += __shfl_xor(p0, off);
      p1 += __shfl_xor(p1, off);
    }
    if (lane == 0) {
      float v0 = p0 + Wc[256], v1 = p1 + Wc[257];
      float m = fmaxf(v0, v1);
      float ls = m + logf(__expf(v0 - m) + __expf(v1 - m));
      size_t base = (size_t)NN * 128 + (size_t)v * 2;
      if (flag[0]) {
        ((float*)dout)[base + 0] = v0 - ls;
        ((float*)dout)[base + 1] = v1 - ls;
      } else {
        unsigned pk = (unsigned)f2bf(v0 - ls) | ((unsigned)f2bf(v1 - ls) << 16);
        *(unsigned*)((u16*)dout + base) = pk;
      }
    }
  } else {
    float x0 = fmaxf(y0, 0.f), x1 = fmaxf(y1, 0.f);
    float s_ = x0 + x1;
#pragma unroll
    for (int off = 32; off; off >>= 1) s_ += __shfl_xor(s_, off);
    float mean = s_ * (1.f / 128.f);
    float e0 = x0 - mean, e1 = x1 - mean;
    float vv = e0 * e0 + e1 * e1;
#pragma unroll
    for (int off = 32; off; off >>= 1) vv += __shfl_xor(vv, off);
    float inv = 1.f / sqrtf(vv * (1.f / 128.f) + 1e-5f);
    unsigned pk = (unsigned)f2bf(e0 * inv * g[c0] + b[c0]) |
                  ((unsigned)f2bf(e1 * inv * g[c0 + 1] + b[c0 + 1]) << 16);
    *(unsigned*)(out_bf + (size_t)v * 128 + c0) = pk;
  }
}

// ---------------------------------------------------------------- launch
extern "C" void kernel_launch(void* const* d_in, const int* in_sizes, int n_in,
                              void* d_out, int out_size, void* d_ws, size_t ws_size,
                              hipStream_t stream) {
  const int* idx_lp = (const int*)d_in[0];
  const int* len_lp = (const int*)d_in[1];
  const int* idx_ns = (const int*)d_in[2];
  const int* len_ns = (const int*)d_in[3];
  const void* x_ref = d_in[4];
  const void* x_def = d_in[5];
  const void* x_pdt = d_in[6];
  const int* eidx   = (const int*)d_in[7];
  const void* ew    = d_in[8];
  const void* lp_emb = d_in[9];
  const void* ns_emb = d_in[10];

  // ---- workspace layout ----
  char* cur = (char*)d_ws;
  auto alloc = [&](size_t bytes, size_t align) -> void* {
    size_t a = ((size_t)cur + align - 1) & ~(align - 1);
    cur = (char*)(a + bytes);
    return (void*)a;
  };
  int* flag     = (int*)alloc(64, 64);
  float* smallW = (float*)alloc(3104 * 4, 16);
  float* f_Wc   = (float*)alloc(260 * 4, 16);     // combined mp head [2][128]+bc
  float* f_dinv = (float*)alloc(NN * 4, 16);
  int* counts   = (int*)alloc(NN * 4, 16);
  int* startA   = (int*)alloc((NN + 1) * 4, 16);
  int* cursorE  = (int*)alloc(NN * 4, 16);
  int* bins     = (int*)alloc(128 * 4, 16);
  int* perm_lp  = (int*)alloc(PP * NN * 4, 16);
  int* perm_ns  = (int*)alloc(NN * 4, 16);
  int2* csr2    = (int2*)alloc((size_t)EE * 8, 16);
  u16* ub       = (u16*)alloc((size_t)20233216 * 2, 16);
  u16* embbf_lp = ub;
  u16* embbf_ns = ub + 640000;
  u16* wg_lpih  = ub + 1920000;
  u16* wg_lphh  = ub + 1969152;
  u16* wg_nsih  = ub + 2018304;
  u16* wg_nshh  = ub + 2067456;
  u16* wg_lpfc  = ub + 2116608;
  u16* wg_allfc = ub + 2165760;
  u16* wg_c1    = ub + 2247680;
  u16* wg_c2    = ub + 2264064;
  u16* wg_c3    = ub + 2280448;
  u16* hbf_lp   = ub + 2313216;   // [3N,128]
  u16* hbf_ns   = ub + 9993216;   // [N,128]
  u16* lp_bf    = ub + 12553216;  // [N,128]
  u16* xcur_bf  = ub + 15113216;  // [N,128]
  u16* xw_bf    = ub + 17673216;  // [N,128]

  static const int fn[16] = {384, 384, 384, 384, 128, 128, 128, 128,
                             128, 128, 128, 128, 128, 128, 256, 2};
  static const int fsrc[16] = {13, 14, 17, 18, 20, 22, 24, 26,
                               28, 29, 30, 31, 32, 34, 35, 36};
  CvtJobs jf;
  int foff[16];
  {
    int off = 0;
    for (int j = 0; j < 16; ++j) {
      jf.src[j] = d_in[fsrc[j]];
      jf.off[j] = off;
      jf.n[j] = fn[j];
      foff[j] = off;
      off += fn[j];
    }
  }
  float* b_lpbih = smallW + foff[0];
  float* b_lpbhh = smallW + foff[1];
  float* b_nsbih = smallW + foff[2];
  float* b_nsbhh = smallW + foff[3];
  float* b_lpfc  = smallW + foff[4];
  float* b_allfc = smallW + foff[5];
  float* b_conv[3] = {smallW + foff[6], smallW + foff[7], smallW + foff[8]};
  float* g_ln[2] = {smallW + foff[9], smallW + foff[11]};
  float* b_ln[2] = {smallW + foff[10], smallW + foff[12]};

  // job 11 (mp1 weight) removed — its consumer (mp1 GEMM) was collapsed
  static const int bn[12] = {640000, 1280000, 49152, 49152, 49152, 49152,
                             49152, 81920, 16384, 16384, 16384, 0};
  static const int bsrc[12] = {9, 10, 11, 12, 15, 16, 19, 21, 23, 25, 27, 33};
  static const int boff[12] = {0, 640000, 1920000, 1969152, 2018304, 2067456,
                               2116608, 2165760, 2247680, 2264064, 2280448,
                               2296832};
  CvtJobsB jb;
  for (int j = 0; j < 12; ++j) {
    jb.src[j] = d_in[bsrc[j]];
    jb.off[j] = boff[j];
    jb.n[j] = bn[j];
    // jobs 2..5 are the GRU weight matrices [3*128 x 128]:
    // pre-scale r,z gate rows (first 32768 elems) by -log2e, n rows by -2log2e
    const bool gw = (j >= 2 && j <= 5);
    jb.thr[j] = gw ? 32768 : 0;
    jb.scA[j] = gw ? -1.44269504088896f : 1.f;
    jb.scB[j] = gw ? -2.88539008177793f : 1.f;
  }

  const int* e_src = eidx;
  const int* e_dst = eidx + EE;

  // 0. dtype detection (+ bins zero) + counts zero in tail blocks
  const int initBlocks = (NN + 255) / 256;
  k_detect<<<1 + initBlocks, 256, 0, stream>>>(lp_emb, flag, bins, counts);

  // 1. mega-convert: cvt jobs + LP/NS length hist + edge hist + Wc (one launch)
  const int lenBlocks = (PP * NN + 255) / 256;
  const int histBlocks = (EE + 255) / 256;
  k_megacvt<<<12 * 64 + 16 + lenBlocks + histBlocks + 1, 256, 0, stream>>>(
      jb, jf, ub, smallW, len_lp, len_ns, bins, e_dst, counts,
      d_in[35], d_in[34], d_in[36], d_in[33], f_Wc, flag);

  // 2. length fill (local scan per block; zero-based cursors from detect)
  k_lenfillboth<<<lenBlocks, 256, 0, stream>>>(len_lp, len_ns, bins,
                                               perm_lp, perm_ns);

  // 3. merged GRUs (block 0 = CSR offset scan, hidden under gru)
  const int nbLP = PP * NN / 32, nbNS = NN / 32;
  k_gru5<<<1 + nbLP + nbNS, 512, 0, stream>>>(
      perm_lp, perm_ns, nbNS, embbf_lp, embbf_ns,
      (const u16*)lp_emb, (const u16*)ns_emb,
      idx_lp, idx_ns, len_lp, len_ns,
      wg_lpih, wg_lphh, wg_nsih, wg_nshh, b_lpbih, b_lpbhh, b_nsbih, b_nsbhh,
      hbf_lp, hbf_ns, nbLP, counts, startA, cursorE, flag);

  const int gg = (NN + 31) / 32;  // 32-row tiles, 128-thr blocks
  const int fillBlocks = (EE + 127) / 128;
  const int degBlocks = (NN + 127) / 128;
  // 4. lp_fc GEMM (+ raw CSR fill in tail; csr not read until all_fc tail)
  k_gemm_mfma<<<gg + fillBlocks, 128, 0, stream>>>(
      hbf_lp, nullptr, nullptr, nullptr, nullptr, 0, 384, wg_lpfc, b_lpfc,
      lp_bf, 1, NN, flag, e_src, e_dst, ew, cursorE, csr2, nullptr, nullptr,
      EE, 1, gg);
  // 5. all_fc GEMM (+ no-atomic deg-sum/dinv in tail; dinv not read until gather)
  k_gemm_mfma<<<gg + degBlocks, 128, 0, stream>>>(
      x_pdt, x_ref, x_def, lp_bf, hbf_ns, 1, 640, wg_allfc, b_allfc,
      xcur_bf, 1, NN, flag, nullptr, nullptr, nullptr, nullptr, csr2, startA,
      f_dinv, NN, 2, gg);

  // 6. three GCN layers (last gather fuses emb-out + mp head)
  const u16* wgc[3] = {wg_c1, wg_c2, wg_c3};
  for (int l = 0; l < 3; ++l) {
    k_gemm_mfma<<<gg, 128, 0, stream>>>(
        xcur_bf, nullptr, nullptr, nullptr, nullptr, 0, DD, wgc[l], nullptr,
        xw_bf, 1, NN, flag, nullptr, nullptr, nullptr, nullptr, nullptr,
        nullptr, nullptr, 0, 0, gg);
    if (l < 2) {
      k_gcn_gather<<<NN / 4, 256, 0, stream>>>(startA, csr2, f_dinv, xw_bf,
                                               b_conv[l], g_ln[l], b_ln[l],
                                               xcur_bf, nullptr, nullptr,
                                               flag, 0);
    } else {
      k_gcn_gather<<<NN / 4, 256, 0, stream>>>(startA, csr2, f_dinv, xw_bf,
                                               b_conv[l], nullptr, nullptr,
                                               nullptr, d_out, f_Wc,
                                               flag, 1);
    }
  }
}

// Round 13
// 799.689 us; speedup vs baseline: 1.0613x; 1.0291x over previous
//
#include <hip/hip_runtime.h>
#include <math.h>

typedef unsigned short u16;
typedef short bf16x4 __attribute__((ext_vector_type(4)));
typedef short bf16x8 __attribute__((ext_vector_type(8)));
typedef float f32x16 __attribute__((ext_vector_type(16)));

#define NN 20000
#define PP 3
#define TLP 10
#define TNS 20
#define DD 128
#define EE 640000

__device__ __forceinline__ float bf2f(u16 u) {
  union { unsigned u; float f; } v; v.u = ((unsigned)u) << 16; return v.f;
}
__device__ __forceinline__ u16 f2bf(float f) {
  union { float f; unsigned u; } v; v.f = f;
  unsigned r = v.u + 0x7fffu + ((v.u >> 16) & 1u);
  return (u16)(r >> 16);
}
// HW bf16 convert via compiler-visible fptrunc (RNE, hazard-managed).
// Safe on MFMA accumulator reads (unlike inline-asm cvtpk).
__device__ __forceinline__ short f2bf_hw(float f) {
  __bf16 b = (__bf16)f;
  return (short)__builtin_bit_cast(unsigned short, b);
}
__device__ __forceinline__ float loadf(const void* p, size_t i, int isf) {
  return isf ? ((const float*)p)[i] : bf2f(((const u16*)p)[i]);
}
// exp2-domain transcendentals via intrinsics (hazards compiler-managed)
__device__ __forceinline__ float fex2(float x) { return __builtin_amdgcn_exp2f(x); }
__device__ __forceinline__ float frcp(float x) { return __builtin_amdgcn_rcpf(x); }
// packed bf16 convert — ONLY on plain-VALU-produced values (m214-proven).
// NEVER on direct MFMA accumulator reads (R1/R2 corruption: asm consumer of
// MFMA dst misses mandatory wait-states).
__device__ __forceinline__ unsigned cvtpk(float lo, float hi) {
  unsigned r; asm("v_cvt_pk_bf16_f32 %0, %1, %2" : "=v"(r) : "v"(lo), "v"(hi));
  return r;
}

// ------------------------------------------------------------- dtype detect
// block 0: probe + zero bins (incl. the zero-based fill cursors);
// blocks 1..: zero counts
__global__ void k_detect(const void* probe, int* flag, int* bins,
                         int* __restrict__ counts) {
  if (blockIdx.x > 0) {
    int i = (blockIdx.x - 1) * 256 + threadIdx.x;
    if (i < NN) counts[i] = 0;
    return;
  }
  __shared__ int any;
  if (threadIdx.x == 0) any = 0;
  __syncthreads();
  if (threadIdx.x < 128) bins[threadIdx.x] = 0;
  const u16* p = (const u16*)probe;
  int bad = 0;
  for (int i = threadIdx.x; i < 4096; i += 256) {
    int e = (p[2 * i] >> 7) & 0xFF;
    if (e >= 0x9F) bad = 1;
  }
  if (bad) atomicOr(&any, 1);
  __syncthreads();
  if (threadIdx.x == 0) flag[0] = any;  // 1 = f32, 0 = bf16
}

// ------------------------------------------------------------- converters
struct CvtJobs {
  const void* src[16];
  int off[16];
  int n[16];
};

struct CvtJobsB {
  const void* src[12];
  int off[12];
  int n[12];
  int thr[12];     // i < thr -> scA else scB
  float scA[12];
  float scB[12];
};

// mega-launch: [0,768) bf16 jobs; [768,784) float jobs; then LP+NS length
// hist; then counts-only edge hist; last block computes the collapsed
// mp-head weights Wc from RAW inputs.
__global__ void k_megacvt(CvtJobsB j, CvtJobs jf, u16* __restrict__ dst,
                          float* __restrict__ fdst,
                          const int* __restrict__ lensLP,
                          const int* __restrict__ lensNS,
                          int* __restrict__ bins,
                          const int* __restrict__ e_dst,
                          int* __restrict__ counts,
                          const void* __restrict__ w2raw,
                          const void* __restrict__ b1raw,
                          const void* __restrict__ b2raw,
                          const void* __restrict__ mp1raw,
                          float* __restrict__ Wc, const int* flag) {
  const int isf = flag[0];
  const int B_CVT = 12 * 64;
  const int B_F = B_CVT + 16;
  const int LEN_B = (PP * NN + 255) / 256;
  const int B_LEN = B_F + LEN_B;
  const int HIST_B = (EE + 255) / 256;
  const int B_HIST = B_LEN + HIST_B;
  const int bx = (int)blockIdx.x;
  const int tid = threadIdx.x;
  if (bx < B_CVT) {
    const int job = bx >> 6;
    if (job < 2 && !isf) return;  // bf16 input: embeddings used in place
    const int chunk = bx & 63;
    const void* s = j.src[job];
    u16* d = dst + j.off[job];
    const int n = j.n[job];
    const int thr = j.thr[job];
    const float sA = j.scA[job], sB = j.scB[job];
    for (int i = chunk * 256 + tid; i < n; i += 64 * 256)
      d[i] = f2bf(loadf(s, i, isf) * (i < thr ? sA : sB));
    return;
  }
  if (bx < B_F) {
    const int job = bx - B_CVT;
    const void* s = jf.src[job];
    float* d = fdst + jf.off[job];
    const int n = jf.n[job];
    for (int i = tid; i < n; i += 256) d[i] = loadf(s, i, isf);
    return;
  }
  if (bx < B_LEN) {
    int sg = (bx - B_F) * 256 + tid;
    int lane = tid & 63;
    int binL = 0, binN = 0;
    if (sg < PP * NN) binL = lensLP[(sg % NN) * PP + sg / NN];
    if (sg < NN) binN = lensNS[sg];
    for (int b = 1; b <= TLP; ++b) {
      unsigned long long m = __ballot(binL == b);
      if (m) {
        int leader = (int)(__ffsll((long long)m) - 1);
        if (lane == leader) atomicAdd(&bins[b], (int)__popcll(m));
      }
    }
    for (int b = 1; b <= TNS; ++b) {
      unsigned long long m = __ballot(binN == b);
      if (m) {
        int leader = (int)(__ffsll((long long)m) - 1);
        if (lane == leader) atomicAdd(&bins[64 + b], (int)__popcll(m));
      }
    }
    return;
  }
  if (bx < B_HIST) {
    int e = (bx - B_LEN) * 256 + tid;
    if (e < EE) atomicAdd(&counts[e_dst[e]], 1);
    return;
  }
  // last block: combined mp-head weights from raw inputs
  const int o = tid >> 7, k = tid & 127;
  float acc = 0.f;
  for (int d2 = 0; d2 < 128; ++d2)
    acc += loadf(w2raw, o * 128 + d2, isf) * loadf(mp1raw, (size_t)d2 * 128 + k, isf);
  Wc[tid] = acc;
  if (tid < 2) {
    float bacc = loadf(b2raw, tid, isf);
    for (int d2 = 0; d2 < 128; ++d2)
      bacc += loadf(w2raw, tid * 128 + d2, isf) * loadf(b1raw, d2, isf);
    Wc[256 + tid] = bacc;
  }
}

// ------------------------------------------------------------- length fill
__global__ void k_lenfillboth(const int* __restrict__ lensLP,
                              const int* __restrict__ lensNS,
                              int* __restrict__ bins,
                              int* __restrict__ permLP,
                              int* __restrict__ permNS) {
  int sg = blockIdx.x * 256 + threadIdx.x;
  int lane = threadIdx.x & 63;
  int binL = 0, binN = 0;
  if (sg < PP * NN) binL = lensLP[(sg % NN) * PP + sg / NN];
  if (sg < NN) binN = lensNS[sg];
  int baseL = 0;
  for (int b = 1; b <= TLP; ++b) {
    unsigned long long m = __ballot(binL == b);
    if (m) {
      int leader = (int)(__ffsll((long long)m) - 1);
      int base = 0;
      if (lane == leader) base = atomicAdd(&bins[32 + b], (int)__popcll(m));
      base = __shfl(base, leader);
      if (binL == b) {
        int rank = (int)__popcll(m & ((1ull << lane) - 1ull));
        permLP[baseL + base + rank] = sg;
      }
    }
    baseL += bins[b];
  }
  int baseN = 0;
  for (int b = 1; b <= TNS; ++b) {
    unsigned long long m = __ballot(binN == b);
    if (m) {
      int leader = (int)(__ffsll((long long)m) - 1);
      int base = 0;
      if (lane == leader) base = atomicAdd(&bins[96 + b], (int)__popcll(m));
      base = __shfl(base, leader);
      if (binN == b) {
        int rank = (int)__popcll(m & ((1ull << lane) - 1ull));
        permNS[baseN + base + rank] = sg;
      }
    }
    baseN += bins[64 + b];
  }
}

// ---------------------------------------------------------------- GRU v13
// gru body unchanged (control). Block 0 runs the CSR offset scan.
__global__ __launch_bounds__(512, 2) void k_gru5(
    const int* __restrict__ permLP, const int* __restrict__ permNS, int nbNS,
    const u16* __restrict__ embLPc, const u16* __restrict__ embNSc,
    const u16* __restrict__ embLPr, const u16* __restrict__ embNSr,
    const int* __restrict__ idxLP, const int* __restrict__ idxNS,
    const int* __restrict__ lenLP, const int* __restrict__ lenNS,
    const u16* __restrict__ WihLP, const u16* __restrict__ WhhLP,
    const u16* __restrict__ WihNS, const u16* __restrict__ WhhNS,
    const float* __restrict__ bihLP, const float* __restrict__ bhhLP,
    const float* __restrict__ bihNS, const float* __restrict__ bhhNS,
    u16* __restrict__ HoutLP, u16* __restrict__ HoutNS, int nbLP,
    const int* __restrict__ counts, int* __restrict__ startA,
    int* __restrict__ cursorE, const int* __restrict__ flag) {
  __shared__ u16 xp[2][3][128][36];   // [slot][gate][d][m] bf16, b64-packed
  __shared__ u16 Hbf2[2][32][132];    // [slot][m][d], pad 132
  __shared__ int ivs[TNS][32];
  __shared__ int rowv[32], outv[32], lenv_s[32];
  __shared__ int Tbs;

  const int tid = threadIdx.x;
  if (blockIdx.x == 0) {
    // CSR offset scan (single block; all 512 threads hit both barriers)
    int* part = (int*)ivs;  // 256-int scratch
    const int C = (NN + 255) / 256;
    if (tid < 256) {
      int base = tid * C;
      int s = 0;
      for (int k = 0; k < C; ++k) {
        int i2 = base + k;
        s += (i2 < NN) ? counts[i2] : 0;
      }
      part[tid] = s;
    }
    __syncthreads();
    if (tid == 0) {
      int acc = 0;
      for (int k = 0; k < 256; ++k) { int v = part[k]; part[k] = acc; acc += v; }
    }
    __syncthreads();
    if (tid < 256) {
      int run = part[tid];
      int base = tid * C;
      for (int k = 0; k < C; ++k) {
        int i2 = base + k;
        if (i2 < NN) {
          int c = counts[i2];
          startA[i2] = run;
          cursorE[i2] = run;
          run += c;
        }
      }
      if (tid == 255) startA[NN] = run;
    }
    return;
  }
  const int bid = blockIdx.x - 1;
  const int isf = flag[0];
  const int isNS = bid < nbNS;
  // longest-first: NS family first, descending within each family
  const int chunk = isNS ? (nbNS - 1 - bid) : (nbLP - 1 - (bid - nbNS));
  const int* perm = isNS ? (permNS + chunk * 32) : (permLP + chunk * 32);
  // bf16 input: embeddings used directly from d_in (identity copy skipped)
  const u16* embbf = isNS ? (isf ? embNSc : embNSr) : (isf ? embLPc : embLPr);
  const int* idx = isNS ? idxNS : idxLP;
  const int* lens = isNS ? lenNS : lenLP;
  const u16* Wih = isNS ? WihNS : WihLP;
  const u16* Whh = isNS ? WhhNS : WhhLP;
  const float* bih = isNS ? bihNS : bihLP;
  const float* bhh = isNS ? bhhNS : bhhLP;
  u16* Hout = isNS ? HoutNS : HoutLP;
  const int T = isNS ? TNS : TLP;

  const int w = tid >> 6, lane = tid & 63;
  const int l31 = lane & 31, lh = lane >> 5;
  const int role = w >> 2;  // 0 = X producer, 1 = H consumer
  const int j = w & 3;
  const int d = 32 * j + l31;

  if (tid < 32) {
    int sg = perm[tid];
    int row = isNS ? sg : ((sg % NN) * PP + sg / NN);
    rowv[tid] = row;
    outv[tid] = sg;
    lenv_s[tid] = lens[row];
  }
  __syncthreads();
  if (tid == 0) {
    int m = 1;
    for (int k = 0; k < 32; ++k) m = max(m, lenv_s[k]);
    Tbs = m;
  }
  __syncthreads();
  const int Tb = Tbs;

  for (int z = tid; z < Tb * 32; z += 512) {
    int s = z & 31, t = z >> 5;
    ivs[t][s] = idx[(size_t)rowv[s] * T + t];
  }
  // zero Hbf2 slot 0 (32*132 u16 = 4224 elems = 2112 u32)
  for (int z = tid; z < 2112; z += 512) ((unsigned*)Hbf2[0])[z] = 0u;

  bf16x8 wf[24];
  {
    const u16* Ws = role ? Whh : Wih;
#pragma unroll
    for (int g = 0; g < 3; ++g)
#pragma unroll
      for (int kb = 0; kb < 8; ++kb)
        wf[g * 8 + kb] =
            *(const bf16x8*)(Ws + (size_t)(128 * g + d) * 128 + kb * 16 + lh * 8);
  }
  // exp2-domain bias folding into accumulator inits
  const float SA = -1.44269504088896f;   // -log2(e)
  const float SN = -2.88539008177793f;   // -2*log2(e)
  float ib0, ib1, ib2;
  if (!role) {
    ib0 = SA * (bih[d] + bhh[d]);
    ib1 = SA * (bih[128 + d] + bhh[128 + d]);
    ib2 = SN * bih[256 + d];
  } else {
    ib0 = 0.f;
    ib1 = 0.f;
    ib2 = SN * bhh[256 + d];
  }

  __syncthreads();
  int lenr[16];
#pragma unroll
  for (int rg = 0; rg < 16; ++rg)
    lenr[rg] = lenv_s[(rg & 3) + 8 * (rg >> 2) + 4 * lh];

  float h[16];
#pragma unroll
  for (int rg = 0; rg < 16; ++rg) h[rg] = 0.f;

  for (int i = 0; i <= Tb; ++i) {
    if (!role) {
      if (i < Tb) {
        bf16x8 Xf[8];
        const u16* erow = embbf + (size_t)ivs[i][l31] * 128 + lh * 8;
#pragma unroll
        for (int kb = 0; kb < 8; ++kb) Xf[kb] = *(const bf16x8*)(erow + kb * 16);
        f32x16 a0 = (f32x16)(ib0), a1 = (f32x16)(ib1), a2 = (f32x16)(ib2);
#pragma unroll
        for (int kb = 0; kb < 8; ++kb) {
          a0 = __builtin_amdgcn_mfma_f32_32x32x16_bf16(Xf[kb], wf[kb], a0, 0, 0, 0);
          a1 = __builtin_amdgcn_mfma_f32_32x32x16_bf16(Xf[kb], wf[8 + kb], a1, 0, 0, 0);
          a2 = __builtin_amdgcn_mfma_f32_32x32x16_bf16(Xf[kb], wf[16 + kb], a2, 0, 0, 0);
        }
        const int sl = i & 1;
#pragma unroll
        for (int rq = 0; rq < 4; ++rq) {
          int mo = 8 * rq + 4 * lh;
          bf16x4 p0, p1, p2;
#pragma unroll
          for (int q = 0; q < 4; ++q) {
            p0[q] = f2bf_hw(a0[4 * rq + q]);
            p1[q] = f2bf_hw(a1[4 * rq + q]);
            p2[q] = f2bf_hw(a2[4 * rq + q]);
          }
          *(bf16x4*)(&xp[sl][0][d][mo]) = p0;
          *(bf16x4*)(&xp[sl][1][d][mo]) = p1;
          *(bf16x4*)(&xp[sl][2][d][mo]) = p2;
        }
      }
    } else {
      if (i >= 1) {
        const int rs = (i - 1) & 1, wsl = i & 1;
        bf16x8 Hf[8];
#pragma unroll
        for (int kb = 0; kb < 8; ++kb) {
          bf16x4 lo = *(const bf16x4*)(&Hbf2[rs][l31][16 * kb + 8 * lh]);
          bf16x4 hi = *(const bf16x4*)(&Hbf2[rs][l31][16 * kb + 8 * lh + 4]);
          Hf[kb] = __builtin_shufflevector(lo, hi, 0, 1, 2, 3, 4, 5, 6, 7);
        }
        f32x16 a0 = (f32x16)(ib0), a1 = (f32x16)(ib1), a2 = (f32x16)(ib2);
#pragma unroll
        for (int kb = 0; kb < 8; ++kb) {
          a0 = __builtin_amdgcn_mfma_f32_32x32x16_bf16(Hf[kb], wf[kb], a0, 0, 0, 0);
          a1 = __builtin_amdgcn_mfma_f32_32x32x16_bf16(Hf[kb], wf[8 + kb], a1, 0, 0, 0);
          a2 = __builtin_amdgcn_mfma_f32_32x32x16_bf16(Hf[kb], wf[16 + kb], a2, 0, 0, 0);
        }
        const int t = i - 1;
#pragma unroll
        for (int rq = 0; rq < 4; ++rq) {
          int mo = 8 * rq + 4 * lh;
          bf16x4 x0 = *(const bf16x4*)(&xp[rs][0][d][mo]);
          bf16x4 x1 = *(const bf16x4*)(&xp[rs][1][d][mo]);
          bf16x4 x2 = *(const bf16x4*)(&xp[rs][2][d][mo]);
          float hq[4];
#pragma unroll
          for (int q = 0; q < 4; ++q) {
            int rg = 4 * rq + q;
            float r = frcp(1.f + fex2(a0[rg] + bf2f((u16)x0[q])));
            float z = frcp(1.f + fex2(a1[rg] + bf2f((u16)x1[q])));
            float s = fmaf(r, a2[rg], bf2f((u16)x2[q]));
            float nn_ = fmaf(2.f, frcp(1.f + fex2(s)), -1.f);
            float hnew = fmaf(z, h[rg] - nn_, nn_);
            h[rg] = (t < lenr[rg]) ? hnew : h[rg];  // pack_padded mask
            hq[q] = h[rg];
          }
          unsigned pa = cvtpk(hq[0], hq[1]);
          unsigned pb = cvtpk(hq[2], hq[3]);
          Hbf2[wsl][mo + 0][d] = (u16)pa;
          Hbf2[wsl][mo + 1][d] = (u16)(pa >> 16);
          Hbf2[wsl][mo + 2][d] = (u16)pb;
          Hbf2[wsl][mo + 3][d] = (u16)(pb >> 16);
        }
      }
    }
    __syncthreads();
  }

  if (role) {
#pragma unroll
    for (int rg = 0; rg < 16; ++rg) {
      int m = (rg & 3) + 8 * (rg >> 2) + 4 * lh;
      Hout[(size_t)outv[m] * 128 + d] = f2bf(h[rg]);
    }
  }
}

// ---------------------------------------------------------------- GEMM (MFMA, LDS-free)
// used for lp_fc (mode 0, K=384) + CSR fill tail
__global__ __launch_bounds__(128) void k_gemm_mfma(
    const void* __restrict__ A0, const void* __restrict__ A1,
    const void* __restrict__ A2, const u16* __restrict__ A3,
    const u16* __restrict__ A4, int mode, int K,
    const u16* __restrict__ W, const float* __restrict__ bias,
    void* __restrict__ Cout, int out_bf, int M, const int* __restrict__ flag,
    const int* __restrict__ esrc, const int* __restrict__ edst,
    const void* __restrict__ ew, int* __restrict__ cursor,
    int2* __restrict__ csr, const int* __restrict__ startT,
    float* __restrict__ dinvOut, int tailN, int tailMode, int gemmBlocks) {
  const int isf = flag[0];
  const int tid = threadIdx.x;
  if ((int)blockIdx.x >= gemmBlocks) {
    int i = ((int)blockIdx.x - gemmBlocks) * 128 + tid;
    if (i < tailN) {
      if (tailMode == 1) {
        int s = esrc[i];
        float wv = loadf(ew, i, isf);
        int p = atomicAdd(&cursor[edst[i]], 1);
        csr[p] = make_int2(s, __float_as_int(wv));
      } else {
        int a = startT[i], b = startT[i + 1];
        float sum = 1.f;  // self-loop weight
        for (int k = a; k < b; ++k) sum += __int_as_float(csr[k].y);
        dinvOut[i] = 1.f / sqrtf(sum);
      }
    }
    return;
  }
  const int w = tid >> 6, lane = tid & 63;
  const int l31 = lane & 31, lh = lane >> 5;
  const int w23 = w;                 // column tile (0..1)
  const int mbase = blockIdx.x * 32; // single 32-row tile per block
  const int row = mbase + l31;
  const int rowc = row < M ? row : M - 1;

  f32x16 acc0 = (f32x16)(0.f), acc1 = (f32x16)(0.f);
  const int nk = K >> 4;
  for (int kb = 0; kb < nk; ++kb) {
    bf16x8 a;
    if (mode == 0) {
      a = *(const bf16x8*)((const u16*)A0 + (size_t)rowc * K + kb * 16 + lh * 8);
    } else {
      int r5 = 5 * rowc + (kb >> 3);
      int slot = r5 / NN;
      int inner = r5 - slot * NN;
      int koff = (kb & 7) * 16 + lh * 8;
      if (slot < 3) {
        const void* p = (slot == 0) ? A0 : (slot == 1) ? A1 : A2;
        if (isf) {
          const float* fp = (const float*)p + (size_t)inner * 128 + koff;
          float4 v0 = *(const float4*)fp;
          float4 v1 = *(const float4*)(fp + 4);
          a[0] = (short)f2bf(v0.x); a[1] = (short)f2bf(v0.y);
          a[2] = (short)f2bf(v0.z); a[3] = (short)f2bf(v0.w);
          a[4] = (short)f2bf(v1.x); a[5] = (short)f2bf(v1.y);
          a[6] = (short)f2bf(v1.z); a[7] = (short)f2bf(v1.w);
        } else {
          a = *(const bf16x8*)((const u16*)p + (size_t)inner * 128 + koff);
        }
      } else {
        const u16* p = (slot == 3) ? A3 : A4;
        a = *(const bf16x8*)(p + (size_t)inner * 128 + koff);
      }
    }
    const u16* wp = W + (size_t)(64 * w23 + l31) * K + kb * 16 + lh * 8;
    bf16x8 b0 = *(const bf16x8*)wp;
    bf16x8 b1 = *(const bf16x8*)(wp + (size_t)32 * K);
    acc0 = __builtin_amdgcn_mfma_f32_32x32x16_bf16(a, b0, acc0, 0, 0, 0);
    acc1 = __builtin_amdgcn_mfma_f32_32x32x16_bf16(a, b1, acc1, 0, 0, 0);
  }
  const int col0 = 64 * w23 + l31;
  const float bv0 = bias ? bias[col0] : 0.f;
  const float bv1 = bias ? bias[col0 + 32] : 0.f;
#pragma unroll
  for (int rg = 0; rg < 16; ++rg) {
    int m = (rg & 3) + 8 * (rg >> 2) + 4 * lh;
    int grow = mbase + m;
    if (grow < M) {
      float v0 = acc0[rg] + bv0, v1 = acc1[rg] + bv1;
      if (out_bf) {
        ((u16*)Cout)[(size_t)grow * 128 + col0] = f2bf(v0);
        ((u16*)Cout)[(size_t)grow * 128 + col0 + 32] = f2bf(v1);
      } else {
        ((float*)Cout)[(size_t)grow * 128 + col0] = v0;
        ((float*)Cout)[(size_t)grow * 128 + col0 + 32] = v1;
      }
    }
  }
}

// ---------------------------------------------- all_fc + conv1-GEMM (fused)
// Row-local fusion: the all_fc tile's 32 output rows are exactly the A-rows
// the conv1 GEMM needs -> stage bf16 tile in LDS, barrier, GEMM from LDS.
// Eliminates the xcur global round-trip. Tail blocks: no-atomic deg+dinv.
__global__ __launch_bounds__(128) void k_allfc_g1(
    const void* __restrict__ A0, const void* __restrict__ A1,
    const void* __restrict__ A2, const u16* __restrict__ A3,
    const u16* __restrict__ A4,
    const u16* __restrict__ W, const float* __restrict__ bias,
    const u16* __restrict__ W1, u16* __restrict__ xwOut,
    const int* __restrict__ flag,
    const int2* __restrict__ csr, const int* __restrict__ startT,
    float* __restrict__ dinvOut, int gemmBlocks) {
  __shared__ u16 ylds[32][136];   // row stride 272B (16B-aligned for b128)
  const int isf = flag[0];
  const int tid = threadIdx.x;
  if ((int)blockIdx.x >= gemmBlocks) {
    int i = ((int)blockIdx.x - gemmBlocks) * 128 + tid;
    if (i < NN) {
      int a = startT[i], b = startT[i + 1];
      float sum = 1.f;  // self-loop weight
      for (int k = a; k < b; ++k) sum += __int_as_float(csr[k].y);
      dinvOut[i] = 1.f / sqrtf(sum);
    }
    return;
  }
  const int w = tid >> 6, lane = tid & 63;
  const int l31 = lane & 31, lh = lane >> 5;
  const int w23 = w;
  const int mbase = blockIdx.x * 32;
  const int rowc = mbase + l31;      // 625*32 == NN exactly

  f32x16 acc0 = (f32x16)(0.f), acc1 = (f32x16)(0.f);
  const int K = 640;
  for (int kb = 0; kb < (K >> 4); ++kb) {
    bf16x8 a;
    {
      int r5 = 5 * rowc + (kb >> 3);
      int slot = r5 / NN;
      int inner = r5 - slot * NN;
      int koff = (kb & 7) * 16 + lh * 8;
      if (slot < 3) {
        const void* p = (slot == 0) ? A0 : (slot == 1) ? A1 : A2;
        if (isf) {
          const float* fp = (const float*)p + (size_t)inner * 128 + koff;
          float4 v0 = *(const float4*)fp;
          float4 v1 = *(const float4*)(fp + 4);
          a[0] = (short)f2bf(v0.x); a[1] = (short)f2bf(v0.y);
          a[2] = (short)f2bf(v0.z); a[3] = (short)f2bf(v0.w);
          a[4] = (short)f2bf(v1.x); a[5] = (short)f2bf(v1.y);
          a[6] = (short)f2bf(v1.z); a[7] = (short)f2bf(v1.w);
        } else {
          a = *(const bf16x8*)((const u16*)p + (size_t)inner * 128 + koff);
        }
      } else {
        const u16* p = (slot == 3) ? A3 : A4;
        a = *(const bf16x8*)(p + (size_t)inner * 128 + koff);
      }
    }
    const u16* wp = W + (size_t)(64 * w23 + l31) * K + kb * 16 + lh * 8;
    bf16x8 b0 = *(const bf16x8*)wp;
    bf16x8 b1 = *(const bf16x8*)(wp + (size_t)32 * K);
    acc0 = __builtin_amdgcn_mfma_f32_32x32x16_bf16(a, b0, acc0, 0, 0, 0);
    acc1 = __builtin_amdgcn_mfma_f32_32x32x16_bf16(a, b1, acc1, 0, 0, 0);
  }
  const int col0 = 64 * w23 + l31;
  const float bv0 = bias[col0], bv1 = bias[col0 + 32];
#pragma unroll
  for (int rg = 0; rg < 16; ++rg) {
    int m = (rg & 3) + 8 * (rg >> 2) + 4 * lh;
    ylds[m][col0] = f2bf(acc0[rg] + bv0);
    ylds[m][col0 + 32] = f2bf(acc1[rg] + bv1);
  }
  __syncthreads();
  // conv1 GEMM from LDS tile
  f32x16 c0a = (f32x16)(0.f), c1a = (f32x16)(0.f);
#pragma unroll
  for (int kb = 0; kb < 8; ++kb) {
    bf16x8 a = *(const bf16x8*)(&ylds[l31][kb * 16 + lh * 8]);
    const u16* wp = W1 + (size_t)(64 * w23 + l31) * 128 + kb * 16 + lh * 8;
    bf16x8 b0 = *(const bf16x8*)wp;
    bf16x8 b1 = *(const bf16x8*)(wp + (size_t)32 * 128);
    c0a = __builtin_amdgcn_mfma_f32_32x32x16_bf16(a, b0, c0a, 0, 0, 0);
    c1a = __builtin_amdgcn_mfma_f32_32x32x16_bf16(a, b1, c1a, 0, 0, 0);
  }
#pragma unroll
  for (int rg = 0; rg < 16; ++rg) {
    int m = (rg & 3) + 8 * (rg >> 2) + 4 * lh;
    xwOut[(size_t)(mbase + m) * 128 + col0] = f2bf(c0a[rg]);
    xwOut[(size_t)(mbase + m) * 128 + col0 + 32] = f2bf(c1a[rg]);
  }
}

// ---------------------------------- fused GCN layer: gather+ReLU+LN -> GEMM
// 512 thr: 8 waves gather 4 vertices each (32-row tile, bf16 into LDS),
// barrier, waves 0-3 run the 32x128 GEMM (32-col tile each) from LDS.
// Row-local: block's gather output rows == its GEMM A rows; no grid sync.
__global__ __launch_bounds__(512) void k_gcnfused(
    const int* __restrict__ start, const int2* __restrict__ csr,
    const float* __restrict__ dinv, const u16* __restrict__ xwIn,
    const float* __restrict__ bias, const float* __restrict__ g,
    const float* __restrict__ b, const u16* __restrict__ Wn,
    u16* __restrict__ xwOut) {
  __shared__ u16 ylds[32][136];   // row stride 272B (16B-aligned for b128)
  const int tid = threadIdx.x;
  const int wv = tid >> 6, lane = tid & 63;
  const int vbase = blockIdx.x * 32;
  const int c0 = 2 * lane;
  // gather phase: 4 vertices sequentially per wave
  for (int s = 0; s < 4; ++s) {
    const int r = wv * 4 + s;
    const int v = vbase + r;
    float acc0 = 0.f, acc1 = 0.f;
    int i = start[v];
    const int i1 = start[v + 1];
    for (; i + 4 <= i1; i += 4) {
      int2 e0 = csr[i], e1 = csr[i + 1], e2 = csr[i + 2], e3 = csr[i + 3];
      unsigned p0 = *(const unsigned*)(xwIn + (size_t)e0.x * 128 + c0);
      unsigned p1 = *(const unsigned*)(xwIn + (size_t)e1.x * 128 + c0);
      unsigned p2 = *(const unsigned*)(xwIn + (size_t)e2.x * 128 + c0);
      unsigned p3 = *(const unsigned*)(xwIn + (size_t)e3.x * 128 + c0);
      float f0 = __int_as_float(e0.y) * dinv[e0.x];
      float f1 = __int_as_float(e1.y) * dinv[e1.x];
      float f2 = __int_as_float(e2.y) * dinv[e2.x];
      float f3 = __int_as_float(e3.y) * dinv[e3.x];
      acc0 += f0 * bf2f((u16)(p0 & 0xffff)) + f1 * bf2f((u16)(p1 & 0xffff)) +
              f2 * bf2f((u16)(p2 & 0xffff)) + f3 * bf2f((u16)(p3 & 0xffff));
      acc1 += f0 * bf2f((u16)(p0 >> 16)) + f1 * bf2f((u16)(p1 >> 16)) +
              f2 * bf2f((u16)(p2 >> 16)) + f3 * bf2f((u16)(p3 >> 16));
    }
    if (i + 2 <= i1) {
      int2 e0 = csr[i], e1 = csr[i + 1];
      unsigned p0 = *(const unsigned*)(xwIn + (size_t)e0.x * 128 + c0);
      unsigned p1 = *(const unsigned*)(xwIn + (size_t)e1.x * 128 + c0);
      float f0 = __int_as_float(e0.y) * dinv[e0.x];
      float f1 = __int_as_float(e1.y) * dinv[e1.x];
      acc0 += f0 * bf2f((u16)(p0 & 0xffff)) + f1 * bf2f((u16)(p1 & 0xffff));
      acc1 += f0 * bf2f((u16)(p0 >> 16)) + f1 * bf2f((u16)(p1 >> 16));
      i += 2;
    }
    if (i < i1) {
      int2 e = csr[i];
      float c = __int_as_float(e.y) * dinv[e.x];
      unsigned pv = *(const unsigned*)(xwIn + (size_t)e.x * 128 + c0);
      acc0 += c * bf2f((u16)(pv & 0xffff));
      acc1 += c * bf2f((u16)(pv >> 16));
    }
    float dv = dinv[v];
    unsigned sv = *(const unsigned*)(xwIn + (size_t)v * 128 + c0);
    float y0 = bias[c0] + dv * (dv * bf2f((u16)(sv & 0xffff)) + acc0);
    float y1 = bias[c0 + 1] + dv * (dv * bf2f((u16)(sv >> 16)) + acc1);
    float x0 = fmaxf(y0, 0.f), x1 = fmaxf(y1, 0.f);
    float s_ = x0 + x1;
#pragma unroll
    for (int off = 32; off; off >>= 1) s_ += __shfl_xor(s_, off);
    float mean = s_ * (1.f / 128.f);
    float e0 = x0 - mean, e1 = x1 - mean;
    float vv = e0 * e0 + e1 * e1;
#pragma unroll
    for (int off = 32; off; off >>= 1) vv += __shfl_xor(vv, off);
    float inv = 1.f / sqrtf(vv * (1.f / 128.f) + 1e-5f);
    unsigned pk = (unsigned)f2bf(e0 * inv * g[c0] + b[c0]) |
                  ((unsigned)f2bf(e1 * inv * g[c0 + 1] + b[c0 + 1]) << 16);
    *(unsigned*)(&ylds[r][c0]) = pk;
  }
  __syncthreads();
  if (wv >= 4) return;
  // GEMM phase: wave wv -> 32-col tile [32*wv, 32*wv+32)
  const int l31 = lane & 31, lh = lane >> 5;
  f32x16 acc = (f32x16)(0.f);
#pragma unroll
  for (int kb = 0; kb < 8; ++kb) {
    bf16x8 a = *(const bf16x8*)(&ylds[l31][kb * 16 + lh * 8]);
    bf16x8 b0 = *(const bf16x8*)(Wn + (size_t)(32 * wv + l31) * 128 + kb * 16 + lh * 8);
    acc = __builtin_amdgcn_mfma_f32_32x32x16_bf16(a, b0, acc, 0, 0, 0);
  }
  const int col0 = 32 * wv + l31;
#pragma unroll
  for (int rg = 0; rg < 16; ++rg) {
    int m = (rg & 3) + 8 * (rg >> 2) + 4 * lh;
    xwOut[(size_t)(vbase + m) * 128 + col0] = f2bf(acc[rg]);
  }
}

// ------------------------------------------------- final GCN gather (mode 1)
// writes emb chunk + collapsed mp head to d_out (unchanged from R10-best).
__global__ __launch_bounds__(256) void k_gcn_gather(
    const int* __restrict__ start, const int2* __restrict__ csr,
    const float* __restrict__ dinv, const u16* __restrict__ xwbf,
    const float* __restrict__ bias,
    void* __restrict__ dout, const float* __restrict__ Wc,
    const int* __restrict__ flag) {
  int v = blockIdx.x * 4 + (threadIdx.x >> 6);
  int lane = threadIdx.x & 63;
  if (v >= NN) return;
  const int c0 = 2 * lane;
  float acc0 = 0.f, acc1 = 0.f;
  int i = start[v];
  const int i1 = start[v + 1];
  for (; i + 4 <= i1; i += 4) {
    int2 e0 = csr[i], e1 = csr[i + 1], e2 = csr[i + 2], e3 = csr[i + 3];
    unsigned p0 = *(const unsigned*)(xwbf + (size_t)e0.x * 128 + c0);
    unsigned p1 = *(const unsigned*)(xwbf + (size_t)e1.x * 128 + c0);
    unsigned p2 = *(const unsigned*)(xwbf + (size_t)e2.x * 128 + c0);
    unsigned p3 = *(const unsigned*)(xwbf + (size_t)e3.x * 128 + c0);
    float f0 = __int_as_float(e0.y) * dinv[e0.x];
    float f1 = __int_as_float(e1.y) * dinv[e1.x];
    float f2 = __int_as_float(e2.y) * dinv[e2.x];
    float f3 = __int_as_float(e3.y) * dinv[e3.x];
    acc0 += f0 * bf2f((u16)(p0 & 0xffff)) + f1 * bf2f((u16)(p1 & 0xffff)) +
            f2 * bf2f((u16)(p2 & 0xffff)) + f3 * bf2f((u16)(p3 & 0xffff));
    acc1 += f0 * bf2f((u16)(p0 >> 16)) + f1 * bf2f((u16)(p1 >> 16)) +
            f2 * bf2f((u16)(p2 >> 16)) + f3 * bf2f((u16)(p3 >> 16));
  }
  if (i + 2 <= i1) {
    int2 e0 = csr[i], e1 = csr[i + 1];
    unsigned p0 = *(const unsigned*)(xwbf + (size_t)e0.x * 128 + c0);
    unsigned p1 = *(const unsigned*)(xwbf + (size_t)e1.x * 128 + c0);
    float f0 = __int_as_float(e0.y) * dinv[e0.x];
    float f1 = __int_as_float(e1.y) * dinv[e1.x];
    acc0 += f0 * bf2f((u16)(p0 & 0xffff)) + f1 * bf2f((u16)(p1 & 0xffff));
    acc1 += f0 * bf2f((u16)(p0 >> 16)) + f1 * bf2f((u16)(p1 >> 16));
    i += 2;
  }
  if (i < i1) {
    int2 e = csr[i];
    float c = __int_as_float(e.y) * dinv[e.x];
    unsigned pv = *(const unsigned*)(xwbf + (size_t)e.x * 128 + c0);
    acc0 += c * bf2f((u16)(pv & 0xffff));
    acc1 += c * bf2f((u16)(pv >> 16));
  }
  float dv = dinv[v];
  unsigned sv = *(const unsigned*)(xwbf + (size_t)v * 128 + c0);
  float y0 = bias[c0] + dv * (dv * bf2f((u16)(sv & 0xffff)) + acc0);
  float y1 = bias[c0 + 1] + dv * (dv * bf2f((u16)(sv >> 16)) + acc1);
  // emb chunk -> d_out directly, in detected dtype
  if (flag[0]) {
    *(float2*)((float*)dout + (size_t)v * 128 + c0) = make_float2(y0, y1);
  } else {
    unsigned pk = (unsigned)f2bf(y0) | ((unsigned)f2bf(y1) << 16);
    *(unsigned*)((u16*)dout + (size_t)v * 128 + c0) = pk;
  }
  // fused mp head on the relu'd row held across the wave
  float x0 = fmaxf(y0, 0.f), x1 = fmaxf(y1, 0.f);
  float p0 = x0 * Wc[c0] + x1 * Wc[c0 + 1];
  float p1 = x0 * Wc[128 + c0] + x1 * Wc[128 + c0 + 1];
#pragma unroll
  for (int off = 32; off; off >>= 1) {
    p0 += __shfl_xor(p0, off);
    p1 += __shfl_xor(p1, off);
  }
  if (lane == 0) {
    float v0 = p0 + Wc[256], v1 = p1 + Wc[257];
    float m = fmaxf(v0, v1);
    float ls = m + logf(__expf(v0 - m) + __expf(v1 - m));
    size_t base = (size_t)NN * 128 + (size_t)v * 2;
    if (flag[0]) {
      ((float*)dout)[base + 0] = v0 - ls;
      ((float*)dout)[base + 1] = v1 - ls;
    } else {
      unsigned pk = (unsigned)f2bf(v0 - ls) | ((unsigned)f2bf(v1 - ls) << 16);
      *(unsigned*)((u16*)dout + base) = pk;
    }
  }
}

// ---------------------------------------------------------------- launch
extern "C" void kernel_launch(void* const* d_in, const int* in_sizes, int n_in,
                              void* d_out, int out_size, void* d_ws, size_t ws_size,
                              hipStream_t stream) {
  const int* idx_lp = (const int*)d_in[0];
  const int* len_lp = (const int*)d_in[1];
  const int* idx_ns = (const int*)d_in[2];
  const int* len_ns = (const int*)d_in[3];
  const void* x_ref = d_in[4];
  const void* x_def = d_in[5];
  const void* x_pdt = d_in[6];
  const int* eidx   = (const int*)d_in[7];
  const void* ew    = d_in[8];
  const void* lp_emb = d_in[9];
  const void* ns_emb = d_in[10];

  // ---- workspace layout ----
  char* cur = (char*)d_ws;
  auto alloc = [&](size_t bytes, size_t align) -> void* {
    size_t a = ((size_t)cur + align - 1) & ~(align - 1);
    cur = (char*)(a + bytes);
    return (void*)a;
  };
  int* flag     = (int*)alloc(64, 64);
  float* smallW = (float*)alloc(3104 * 4, 16);
  float* f_Wc   = (float*)alloc(260 * 4, 16);     // combined mp head [2][128]+bc
  float* f_dinv = (float*)alloc(NN * 4, 16);
  int* counts   = (int*)alloc(NN * 4, 16);
  int* startA   = (int*)alloc((NN + 1) * 4, 16);
  int* cursorE  = (int*)alloc(NN * 4, 16);
  int* bins     = (int*)alloc(128 * 4, 16);
  int* perm_lp  = (int*)alloc(PP * NN * 4, 16);
  int* perm_ns  = (int*)alloc(NN * 4, 16);
  int2* csr2    = (int2*)alloc((size_t)EE * 8, 16);
  u16* ub       = (u16*)alloc((size_t)20233216 * 2, 16);
  u16* embbf_lp = ub;
  u16* embbf_ns = ub + 640000;
  u16* wg_lpih  = ub + 1920000;
  u16* wg_lphh  = ub + 1969152;
  u16* wg_nsih  = ub + 2018304;
  u16* wg_nshh  = ub + 2067456;
  u16* wg_lpfc  = ub + 2116608;
  u16* wg_allfc = ub + 2165760;
  u16* wg_c1    = ub + 2247680;
  u16* wg_c2    = ub + 2264064;
  u16* wg_c3    = ub + 2280448;
  u16* hbf_lp   = ub + 2313216;   // [3N,128]
  u16* hbf_ns   = ub + 9993216;   // [N,128]
  u16* lp_bf    = ub + 12553216;  // [N,128]
  u16* xwA      = ub + 15113216;  // [N,128] ping
  u16* xwB      = ub + 17673216;  // [N,128] pong

  static const int fn[16] = {384, 384, 384, 384, 128, 128, 128, 128,
                             128, 128, 128, 128, 128, 128, 256, 2};
  static const int fsrc[16] = {13, 14, 17, 18, 20, 22, 24, 26,
                               28, 29, 30, 31, 32, 34, 35, 36};
  CvtJobs jf;
  int foff[16];
  {
    int off = 0;
    for (int j = 0; j < 16; ++j) {
      jf.src[j] = d_in[fsrc[j]];
      jf.off[j] = off;
      jf.n[j] = fn[j];
      foff[j] = off;
      off += fn[j];
    }
  }
  float* b_lpbih = smallW + foff[0];
  float* b_lpbhh = smallW + foff[1];
  float* b_nsbih = smallW + foff[2];
  float* b_nsbhh = smallW + foff[3];
  float* b_lpfc  = smallW + foff[4];
  float* b_allfc = smallW + foff[5];
  float* b_conv[3] = {smallW + foff[6], smallW + foff[7], smallW + foff[8]};
  float* g_ln[2] = {smallW + foff[9], smallW + foff[11]};
  float* b_ln[2] = {smallW + foff[10], smallW + foff[12]};

  static const int bn[12] = {640000, 1280000, 49152, 49152, 49152, 49152,
                             49152, 81920, 16384, 16384, 16384, 0};
  static const int bsrc[12] = {9, 10, 11, 12, 15, 16, 19, 21, 23, 25, 27, 33};
  static const int boff[12] = {0, 640000, 1920000, 1969152, 2018304, 2067456,
                               2116608, 2165760, 2247680, 2264064, 2280448,
                               2296832};
  CvtJobsB jb;
  for (int j = 0; j < 12; ++j) {
    jb.src[j] = d_in[bsrc[j]];
    jb.off[j] = boff[j];
    jb.n[j] = bn[j];
    const bool gw = (j >= 2 && j <= 5);
    jb.thr[j] = gw ? 32768 : 0;
    jb.scA[j] = gw ? -1.44269504088896f : 1.f;
    jb.scB[j] = gw ? -2.88539008177793f : 1.f;
  }

  const int* e_src = eidx;
  const int* e_dst = eidx + EE;

  // 0. dtype detection (+ bins zero) + counts zero in tail blocks
  const int initBlocks = (NN + 255) / 256;
  k_detect<<<1 + initBlocks, 256, 0, stream>>>(lp_emb, flag, bins, counts);

  // 1. mega-convert: cvt jobs + LP/NS length hist + edge hist + Wc (one launch)
  const int lenBlocks = (PP * NN + 255) / 256;
  const int histBlocks = (EE + 255) / 256;
  k_megacvt<<<12 * 64 + 16 + lenBlocks + histBlocks + 1, 256, 0, stream>>>(
      jb, jf, ub, smallW, len_lp, len_ns, bins, e_dst, counts,
      d_in[35], d_in[34], d_in[36], d_in[33], f_Wc, flag);

  // 2. length fill (local scan per block; zero-based cursors from detect)
  k_lenfillboth<<<lenBlocks, 256, 0, stream>>>(len_lp, len_ns, bins,
                                               perm_lp, perm_ns);

  // 3. merged GRUs (block 0 = CSR offset scan, hidden under gru)
  const int nbLP = PP * NN / 32, nbNS = NN / 32;
  k_gru5<<<1 + nbLP + nbNS, 512, 0, stream>>>(
      perm_lp, perm_ns, nbNS, embbf_lp, embbf_ns,
      (const u16*)lp_emb, (const u16*)ns_emb,
      idx_lp, idx_ns, len_lp, len_ns,
      wg_lpih, wg_lphh, wg_nsih, wg_nshh, b_lpbih, b_lpbhh, b_nsbih, b_nsbhh,
      hbf_lp, hbf_ns, nbLP, counts, startA, cursorE, flag);

  const int gg = (NN + 31) / 32;  // 32-row tiles
  const int fillBlocks = (EE + 127) / 128;
  const int degBlocks = (NN + 127) / 128;
  // 4. lp_fc GEMM (+ raw CSR fill in tail; csr not read until allfc_g1 tail)
  k_gemm_mfma<<<gg + fillBlocks, 128, 0, stream>>>(
      hbf_lp, nullptr, nullptr, nullptr, nullptr, 0, 384, wg_lpfc, b_lpfc,
      lp_bf, 1, NN, flag, e_src, e_dst, ew, cursorE, csr2, nullptr, nullptr,
      EE, 1, gg);
  // 5. all_fc + conv1-GEMM fused (xcur never hits global) + deg tail -> xwA
  k_allfc_g1<<<gg + degBlocks, 128, 0, stream>>>(
      x_pdt, x_ref, x_def, lp_bf, hbf_ns, wg_allfc, b_allfc, wg_c1, xwA,
      flag, csr2, startA, f_dinv, gg);

  // 6. fused GCN layer 1: gather(xwA)+LN1 -> conv2-GEMM -> xwB
  k_gcnfused<<<gg, 512, 0, stream>>>(startA, csr2, f_dinv, xwA,
                                     b_conv[0], g_ln[0], b_ln[0], wg_c2, xwB);
  // 7. fused GCN layer 2: gather(xwB)+LN2 -> conv3-GEMM -> xwA
  k_gcnfused<<<gg, 512, 0, stream>>>(startA, csr2, f_dinv, xwB,
                                     b_conv[1], g_ln[1], b_ln[1], wg_c3, xwA);
  // 8. final gather (emb-out + collapsed mp head) from xwA
  k_gcn_gather<<<NN / 4, 256, 0, stream>>>(startA, csr2, f_dinv, xwA,
                                           b_conv[2], d_out, f_Wc, flag);
}